// Round 15
// baseline (1599.763 us; speedup 1.0000x reference)
//
#include <hip/hip_runtime.h>
#include <stdint.h>

#define DEV __device__ __forceinline__

typedef short bf16x8 __attribute__((ext_vector_type(8)));
typedef float f32x4 __attribute__((ext_vector_type(4)));

DEV unsigned short f2bf(float f) {
  union { float f; uint32_t u; } v; v.f = f;
  return (unsigned short)((v.u + 0x7fffu + ((v.u >> 16) & 1u)) >> 16);
}
DEV float bf2f(unsigned short u) {
  union { uint32_t u; float f; } v; v.u = (uint32_t)u << 16; return v.f;
}

DEV float fsig(float x) { return 1.f / (1.f + __expf(-x)); }
DEV float ftanh(float x) { float e = __expf(2.f * x); return 1.f - 2.f / (e + 1.f); }

DEV void gload16(const void* g, void* lds) {
  __builtin_amdgcn_global_load_lds(
      (const __attribute__((address_space(1))) int*)(uintptr_t)g,
      (__attribute__((address_space(3))) int*)(uintptr_t)lds, 16, 0, 0);
}

// ================= batched NT GEMM: up to 4 jobs per launch =================
struct GJob {
  const unsigned short* A; const unsigned short* B;
  void *P0, *P1, *P2, *P3;
  const float* bias;
  int lda, ldb, ldc, ldc2, K, Nreal, gx, mode, wg_end, pad;
};
struct GJobs { GJob j[4]; };

__global__ __launch_bounds__(256) void gemm_batch(GJobs JB) {
  int ji = 0;
  while ((int)blockIdx.x >= JB.j[ji].wg_end) ++ji;
  const GJob J = JB.j[ji];
  const int wg = blockIdx.x - (ji ? JB.j[ji - 1].wg_end : 0);

  __shared__ alignas(16) unsigned short Asm[128 * 32];
  __shared__ alignas(16) unsigned short Bsm[128 * 32];
  const int tid = threadIdx.x;
  const int wave = tid >> 6, lane = tid & 63;
  const int m0 = (wg % J.gx) * 128, n0 = (wg / J.gx) * 128;
  const int wr = wave >> 1, wc = wave & 1;

  f32x4 acc[4][4] = {};

  const int q0 = tid, q1 = tid + 256;
  const unsigned short* Ag0 = J.A + (size_t)(m0 + (q0 >> 2)) * J.lda + (q0 & 3) * 8;
  const unsigned short* Ag1 = J.A + (size_t)(m0 + (q1 >> 2)) * J.lda + (q1 & 3) * 8;
  const unsigned short* Bg0 = J.B + (size_t)(n0 + (q0 >> 2)) * J.ldb + (q0 & 3) * 8;
  const unsigned short* Bg1 = J.B + (size_t)(n0 + (q1 >> 2)) * J.ldb + (q1 & 3) * 8;
  char* As0 = (char*)Asm + wave * 1024;  char* As1 = As0 + 4096;
  char* Bs0 = (char*)Bsm + wave * 1024;  char* Bs1 = Bs0 + 4096;

  const int ra = wr * 64 + (lane & 15);
  const int rb = wc * 64 + (lane & 15);
  const int kb = (lane >> 4) * 16;

  for (int k0 = 0; k0 < J.K; k0 += 32) {
    gload16(Ag0 + k0, As0);
    gload16(Ag1 + k0, As1);
    gload16(Bg0 + k0, Bs0);
    gload16(Bg1 + k0, Bs1);
    __syncthreads();
    bf16x8 af[4], bfr[4];
#pragma unroll
    for (int i = 0; i < 4; ++i)
      af[i] = *(const bf16x8*)((const char*)Asm + (ra + i * 16) * 64 + kb);
#pragma unroll
    for (int i = 0; i < 4; ++i)
      bfr[i] = *(const bf16x8*)((const char*)Bsm + (rb + i * 16) * 64 + kb);
#pragma unroll
    for (int mi = 0; mi < 4; ++mi)
#pragma unroll
      for (int ni = 0; ni < 4; ++ni)
        acc[mi][ni] = __builtin_amdgcn_mfma_f32_16x16x32_bf16(af[mi], bfr[ni], acc[mi][ni], 0, 0, 0);
    __syncthreads();
  }

  const int row0 = m0 + wr * 64 + (lane >> 4) * 4;
  const int col0 = n0 + wc * 64 + (lane & 15);

  if (J.mode == 2) {
#pragma unroll
    for (int mi = 0; mi < 4; ++mi) {
      const int rowb = row0 + mi * 16;       // multiple of 4
      const int dd = rowb >> 2;
      const float4 b4 = *(const float4*)&J.bias[rowb];
#pragma unroll
      for (int ni = 0; ni < 4; ++ni) {
        const int col = col0 + ni * 16;
        const int tt = col & 63, bb = col >> 6;
        float4 v;
        v.x = acc[mi][ni][0] + b4.x;
        v.y = acc[mi][ni][1] + b4.y;
        v.z = acc[mi][ni][2] + b4.z;
        v.w = acc[mi][ni][3] + b4.w;
        const int wgid = (bb >> 4) * 16 + (dd >> 5);
        const int ww = (dd >> 3) & 3, mi2 = (dd >> 2) & 1, ln = (dd & 3) * 16 + (bb & 15);
        ((float4*)J.P0)[((((size_t)tt * 128 + wgid) * 4 + ww) * 2 + mi2) * 64 + ln] = v;
      }
    }
    return;
  }

#pragma unroll
  for (int mi = 0; mi < 4; ++mi) {
#pragma unroll
    for (int ni = 0; ni < 4; ++ni) {
      const int col = col0 + ni * 16;
      if (col >= J.Nreal) continue;
      const float bs = J.bias ? J.bias[col] : 0.f;
#pragma unroll
      for (int rr = 0; rr < 4; ++rr) {
        const int row = row0 + mi * 16 + rr;
        const float v = acc[mi][ni][rr] + bs;
        if (J.mode == 1) {
          ((unsigned short*)J.P0)[(size_t)row * J.ldc + col] = f2bf(v);
          if (J.P1) ((unsigned short*)J.P1)[(size_t)row * J.ldc2 + col] = f2bf(v);
        } else if (J.mode == 4) {
          const unsigned short ad = ((const unsigned short*)J.P1)[(size_t)row * J.ldc2 + col];
          ((unsigned short*)J.P0)[(size_t)row * J.ldc + col] = f2bf(v + bf2f(ad));
        } else {  // mode 3
          const int seg = col >> 9, cc = col & 511;
          if (seg == 0)      ((unsigned short*)J.P0)[(size_t)row * 512 + cc] = f2bf(v);
          else if (seg == 1) ((float*)J.P1)[(size_t)row * 512 + cc] = v;
          else if (seg == 2) ((unsigned short*)J.P2)[(size_t)row * 512 + cc] = f2bf(v);
          else               ((float*)J.P3)[(size_t)row * 512 + cc] = v;
        }
      }
    }
  }
}

// ============ 256x256 tile GEMM, BK=64, counted vmcnt pipeline ============
// NEW: LDS-transposed epilogue -- accumulators staged through the (now free)
// 128KB pipeline LDS with XOR bank-swizzle, then fully coalesced float4 NT
// stores (16B/lane) with bias added in the read pass.
__global__ __launch_bounds__(512, 2) void gemm256(
    const unsigned short* __restrict__ A, int lda,
    const unsigned short* __restrict__ B, int ldb,
    float* __restrict__ C, int ldc,
    const float* __restrict__ bias, int K, int Nreal)
{
  __shared__ alignas(16) unsigned short Lds[2][2][16384];
  const int tid = threadIdx.x;
  const int wave = tid >> 6, lane = tid & 63;
  const int fr = lane & 15, kq = lane >> 4;

  const int gx = gridDim.x;
  const int lin = blockIdx.y * gx + blockIdx.x;
  const int nwg = gx * gridDim.y;
  const int q8 = nwg >> 3, r8 = nwg & 7;
  const int xcd = lin & 7, i2 = lin >> 3;
  const int wg = (xcd < r8 ? xcd * (q8 + 1) : r8 * (q8 + 1) + (xcd - r8) * q8) + i2;
  const int m0 = (wg % gx) * 256, n0 = (wg / gx) * 256;

  const int wr = wave >> 2, wc = wave & 3;

  const unsigned short* srcA[4];
  const unsigned short* srcB[4];
  int dstO[4];
#pragma unroll
  for (int s = 0; s < 4; ++s) {
    const int c = tid + s * 512;
    const int row = c >> 3, qp = (c & 7) ^ (row & 7);
    srcA[s] = A + (size_t)(m0 + row) * lda + qp * 8;
    srcB[s] = B + (size_t)(n0 + row) * ldb + qp * 8;
    dstO[s] = (wave * 64 + s * 512) * 16;
  }

  const int NT = K >> 6;
#define STAGE256(kt, buf)                                            \
  {                                                                  \
    _Pragma("unroll")                                                \
    for (int s = 0; s < 4; ++s)                                      \
      gload16(srcA[s] + (kt) * 64, (char*)&Lds[buf][0][0] + dstO[s]);\
    _Pragma("unroll")                                                \
    for (int s = 0; s < 4; ++s)                                      \
      gload16(srcB[s] + (kt) * 64, (char*)&Lds[buf][1][0] + dstO[s]);\
  }
  STAGE256(0, 0);
  STAGE256(1, 1);

  f32x4 acc[8][4] = {};
  const int slot0 = (kq ^ (fr & 7)) * 16;

  for (int kt = 0; kt < NT; ++kt) {
    asm volatile("s_waitcnt vmcnt(8)" ::: "memory");
    __builtin_amdgcn_sched_barrier(0);
    __builtin_amdgcn_s_barrier();
    __builtin_amdgcn_sched_barrier(0);
    const char* bufA = (const char*)&Lds[kt & 1][0][0];
    const char* bufB = (const char*)&Lds[kt & 1][1][0];
    bf16x8 Bf[4][2];
#pragma unroll
    for (int n = 0; n < 4; ++n) {
      const char* bb = bufB + (wc * 64 + n * 16 + fr) * 128;
      Bf[n][0] = *(const bf16x8*)(bb + slot0);
      Bf[n][1] = *(const bf16x8*)(bb + (slot0 ^ 64));
    }
#pragma unroll
    for (int q = 0; q < 4; ++q) {
      bf16x8 Af[2][2];
#pragma unroll
      for (int m2 = 0; m2 < 2; ++m2) {
        const char* ab = bufA + (wr * 128 + q * 32 + m2 * 16 + fr) * 128;
        Af[m2][0] = *(const bf16x8*)(ab + slot0);
        Af[m2][1] = *(const bf16x8*)(ab + (slot0 ^ 64));
      }
      __builtin_amdgcn_s_setprio(1);
#pragma unroll
      for (int m2 = 0; m2 < 2; ++m2)
#pragma unroll
        for (int n = 0; n < 4; ++n) {
          acc[q * 2 + m2][n] = __builtin_amdgcn_mfma_f32_16x16x32_bf16(
              Af[m2][0], Bf[n][0], acc[q * 2 + m2][n], 0, 0, 0);
          acc[q * 2 + m2][n] = __builtin_amdgcn_mfma_f32_16x16x32_bf16(
              Af[m2][1], Bf[n][1], acc[q * 2 + m2][n], 0, 0, 0);
        }
      __builtin_amdgcn_s_setprio(0);
    }
    __builtin_amdgcn_sched_barrier(0);
    __builtin_amdgcn_s_barrier();
    __builtin_amdgcn_sched_barrier(0);
    const int kn = (kt + 2 < NT) ? kt + 2 : 0;
    STAGE256(kn, kt & 1);
  }

  // ---- LDS-transposed coalesced epilogue ----
  asm volatile("s_waitcnt vmcnt(0)" ::: "memory");  // dummy tail loads landed
  __builtin_amdgcn_s_barrier();
  float* scratch = (float*)&Lds[0][0][0];           // 128 rows x 256 cols f32
#pragma unroll
  for (int half = 0; half < 2; ++half) {
    if (wr == half) {
#pragma unroll
      for (int mf = 0; mf < 8; ++mf) {
        const int rbase = mf * 16 + kq * 4;
#pragma unroll
        for (int n = 0; n < 4; ++n) {
          const int c = wc * 64 + n * 16 + fr;
#pragma unroll
          for (int rr = 0; rr < 4; ++rr) {
            const int r = rbase + rr;
            // XOR swizzle in 16B units: spreads 1KB row stride across banks
            scratch[r * 256 + ((((c >> 2) ^ (r & 7)) << 2) | (c & 3))] = acc[mf][n][rr];
          }
        }
      }
    }
    __syncthreads();
    {
      const int lr = tid >> 2;              // 0..127
      const int cseg = (tid & 3) * 64;      // 0,64,128,192
      float* Crow = C + (size_t)(m0 + half * 128 + lr) * ldc;
#pragma unroll
      for (int i = 0; i < 16; ++i) {
        const int col = n0 + cseg + i * 4;
        if (col < Nreal) {
          const int u = ((cseg >> 2) + i) ^ (lr & 7);
          f32x4 v = *(const f32x4*)&scratch[lr * 256 + (u << 2)];
          const f32x4 bb = *(const f32x4*)&bias[col];
          v += bb;
          __builtin_nontemporal_store(v, (f32x4*)&Crow[col]);
        }
      }
    }
    __syncthreads();
  }
#undef STAGE256
}

// ================= fused persistent LSTM1+LSTM2 (256 WGs, 1/CU) =================
// R13-exact (AGENT-scope LLC exchange, split phase B, late fl2 poll).
__global__ __launch_bounds__(256, 1) void lstm_fused(
    const unsigned short* __restrict__ Whh1, const unsigned short* __restrict__ Whh2,
    const unsigned short* __restrict__ Weff2r,  // [16 s][16 kk][2 mi][256 tid][8] bf16
    const unsigned short* __restrict__ h01, const unsigned short* __restrict__ h02,
    const float* __restrict__ c1st, const float* __restrict__ c2st,
    const float* __restrict__ xpr,              // [64][128][4][2][64][4] f32
    const float* __restrict__ beff2,            // [2048] gate-interleaved
    unsigned short* __restrict__ hx1, unsigned short* __restrict__ hx2,
    unsigned short* __restrict__ hcat,          // [8192][1024]: [h2s | h1s]
    int* __restrict__ flags)                    // [2][8][16] ints
{
  __shared__ unsigned short Wsm[8][128][64];
  __shared__ uint32_t Hst[16][16];              // packed h staging (1KB)
  const int tid = threadIdx.x;
  const bool role2 = blockIdx.x >= 128;
  const int wg = role2 ? blockIdx.x - 128 : blockIdx.x;
  const int g = wg >> 4, s = wg & 15;
  const int w = tid >> 6, lane = tid & 63, fr = lane & 15, kq = lane >> 4;

  // ---- stage Whh slice into LDS (slot = chunk ^ (m&7)) ----
  {
    const unsigned short* Whh = role2 ? Whh2 : Whh1;
    const int m = tid >> 1;
    const int row = (m & 3) * 512 + s * 32 + (m >> 2);
    const unsigned short* src = Whh + (size_t)row * 512 + (tid & 1) * 256;
#pragma unroll 4
    for (int cc = 0; cc < 32; ++cc) {
      const int k = (tid & 1) * 256 + cc * 8;
      uint4 v = *(const uint4*)(src + cc * 8);
      const int kblk = k >> 6, c = (k & 63) >> 3, sl = c ^ (m & 7);
      *(uint4*)((char*)&Wsm[kblk][m][0] + sl * 16) = v;
    }
  }

  const int b = g * 16 + fr;
  const int d0 = s * 32 + w * 8 + kq;
  const float* c0 = role2 ? c2st : c1st;
  float c_r[2];
  c_r[0] = c0[b * 512 + d0];
  c_r[1] = c0[b * 512 + d0 + 4];
  __syncthreads();

  int* fl1 = flags + g * 16;
  int* fl2 = flags + 128 + g * 16;
  int* flown = role2 ? fl2 : fl1;
  unsigned short* hxown = role2 ? hx2 : hx1;
  const unsigned short* hinit = role2 ? h02 : h01;
  const int colbase = (role2 ? 0 : 512) + s * 32;
  const float4* xv = (const float4*)xpr + ((size_t)(wg * 4 + w) * 2) * 64 + lane;
  float4 be0 = {0, 0, 0, 0}, be1 = {0, 0, 0, 0};
  if (role2) {
    be0 = *(const float4*)(beff2 + s * 128 + w * 32 + kq * 4);
    be1 = *(const float4*)(beff2 + s * 128 + w * 32 + 16 + kq * 4);
  }
  const size_t hxg = (size_t)g * 8192;           // per-t region offset for group

  for (int t = 0; t < 64; ++t) {
    f32x4 acc[2] = {};
    float4 xg0, xg1;

    if (!role2) {
      xg0 = xv[(size_t)t * 65536];               // HBM prefetch before poll
      xg1 = xv[(size_t)t * 65536 + 64];
      // ---- poll: own group's h1(t-1) posted ----
      if (t) {
        if (w == 1) {
          for (;;) {
            bool ok = true;
            if (lane < 16)
              ok = __hip_atomic_load(fl1 + lane, __ATOMIC_RELAXED,
                                     __HIP_MEMORY_SCOPE_AGENT) >= t;
            if (__all(ok)) break;
            __builtin_amdgcn_s_sleep(1);
          }
        }
        __syncthreads();
      }
      // ---- own-h fragments ----
      bf16x8 hf[16];
      if (t == 0) {
#pragma unroll
        for (int kk = 0; kk < 16; ++kk)
          hf[kk] = *(const bf16x8*)(hinit + (size_t)b * 512 + kk * 32 + kq * 8);
      } else {
        const unsigned short* hb = hx1 + (size_t)(t - 1) * 65536 + hxg + fr * 32 + kq * 8;
#pragma unroll
        for (int kk = 0; kk < 16; ++kk)
          hf[kk] = *(const bf16x8*)(hb + kk * 512);
      }
      // ---- phase A: Whh1 @ h1 (LDS) ----
#pragma unroll
      for (int kk = 0; kk < 16; ++kk) {
        const int kblk = kk >> 1, cbase = (kk & 1) * 4 + kq;
#pragma unroll
        for (int mi = 0; mi < 2; ++mi) {
          const int m = w * 32 + mi * 16 + fr;
          const int sl = cbase ^ (m & 7);
          const bf16x8 af = *(const bf16x8*)((const char*)&Wsm[kblk][m][0] + sl * 16);
          acc[mi] = __builtin_amdgcn_mfma_f32_16x16x32_bf16(af, hf[kk], acc[mi], 0, 0, 0);
        }
      }
    } else {
      xg0 = be0; xg1 = be1;
      // ---- poll: h1(t) posted (role1 runs ahead -> usually instant) ----
      if (w == 1) {
        for (;;) {
          bool ok = true;
          if (lane < 16)
            ok = __hip_atomic_load(fl1 + lane, __ATOMIC_RELAXED,
                                   __HIP_MEMORY_SCOPE_AGENT) >= t + 1;
          if (__all(ok)) break;
          __builtin_amdgcn_s_sleep(1);
        }
      }
      __syncthreads();
      const unsigned short* h1b = hx1 + (size_t)t * 65536 + hxg + fr * 32 + kq * 8;
      bf16x8 hf1[16];
#pragma unroll
      for (int kk = 0; kk < 16; ++kk)
        hf1[kk] = *(const bf16x8*)(h1b + kk * 512);
      const bf16x8* wr = (const bf16x8*)Weff2r + (size_t)s * 32 * 256 + tid;
      // ---- phase B first half (kk 0..7) ----
#pragma unroll
      for (int kk = 0; kk < 8; ++kk) {
#pragma unroll
        for (int mi = 0; mi < 2; ++mi)
          acc[mi] = __builtin_amdgcn_mfma_f32_16x16x32_bf16(
              wr[(kk * 2 + mi) * 256], hf1[kk], acc[mi], 0, 0, 0);
      }
      // ---- late poll of own cohort; then ISSUE h2 loads ----
      if (t) {
        if (w == 1) {
          for (;;) {
            bool ok = true;
            if (lane < 16)
              ok = __hip_atomic_load(fl2 + lane, __ATOMIC_RELAXED,
                                     __HIP_MEMORY_SCOPE_AGENT) >= t;
            if (__all(ok)) break;
            __builtin_amdgcn_s_sleep(1);
          }
        }
        __syncthreads();
      }
      bf16x8 hf2[16];
      if (t == 0) {
#pragma unroll
        for (int kk = 0; kk < 16; ++kk)
          hf2[kk] = *(const bf16x8*)(hinit + (size_t)b * 512 + kk * 32 + kq * 8);
      } else {
        const unsigned short* hb = hx2 + (size_t)(t - 1) * 65536 + hxg + fr * 32 + kq * 8;
#pragma unroll
        for (int kk = 0; kk < 16; ++kk)
          hf2[kk] = *(const bf16x8*)(hb + kk * 512);
      }
      // ---- phase B second half (kk 8..15): covers the h2 LLC fetch ----
#pragma unroll
      for (int kk = 8; kk < 16; ++kk) {
#pragma unroll
        for (int mi = 0; mi < 2; ++mi)
          acc[mi] = __builtin_amdgcn_mfma_f32_16x16x32_bf16(
              wr[(kk * 2 + mi) * 256], hf1[kk], acc[mi], 0, 0, 0);
      }
      // ---- phase A: Whh2 @ h2 (LDS), accumulate ----
#pragma unroll
      for (int kk = 0; kk < 16; ++kk) {
        const int kblk = kk >> 1, cbase = (kk & 1) * 4 + kq;
#pragma unroll
        for (int mi = 0; mi < 2; ++mi) {
          const int m = w * 32 + mi * 16 + fr;
          const int sl = cbase ^ (m & 7);
          const bf16x8 af = *(const bf16x8*)((const char*)&Wsm[kblk][m][0] + sl * 16);
          acc[mi] = __builtin_amdgcn_mfma_f32_16x16x32_bf16(af, hf2[kk], acc[mi], 0, 0, 0);
        }
      }
    }

    // ---- gates (lane-local) ----
    unsigned short hn[2];
#pragma unroll
    for (int mi = 0; mi < 2; ++mi) {
      const float4 xg = mi ? xg1 : xg0;
      const float iv = acc[mi][0] + xg.x;
      const float fv = acc[mi][1] + xg.y;
      const float gv = acc[mi][2] + xg.z;
      const float ov = acc[mi][3] + xg.w;
      const float c = fsig(fv) * c_r[mi] + fsig(iv) * ftanh(gv);
      c_r[mi] = c;
      hn[mi] = f2bf(fsig(ov) * ftanh(c));
    }

    // ---- pack to d-linear order: shfl + perm, stage in LDS ----
    const uint32_t pk = (uint32_t)hn[0] | ((uint32_t)hn[1] << 16);   // (d, d+4)
    const uint32_t y = (uint32_t)__shfl_xor((int)pk, 16);            // partner kq^1
    const uint32_t word = (kq & 1) ? __builtin_amdgcn_perm(pk, y, 0x07060302)
                                   : __builtin_amdgcn_perm(y, pk, 0x05040100);
    Hst[fr][w * 4 + ((kq & 1) ? 2 + (kq >> 1) : (kq >> 1))] = word;
    __syncthreads();

    // ---- wave 0: wide exchange stores (AGENT) + flag + hcat ----
    if (w == 0) {
      const uint4 v = *(const uint4*)&Hst[lane >> 2][(lane & 3) * 4];
      unsigned short* dst = hxown + (size_t)t * 65536 + hxg + s * 512 + lane * 8;
      __hip_atomic_store((unsigned long long*)dst, ((const unsigned long long*)&v)[0],
                         __ATOMIC_RELAXED, __HIP_MEMORY_SCOPE_AGENT);
      __hip_atomic_store((unsigned long long*)(dst + 4), ((const unsigned long long*)&v)[1],
                         __ATOMIC_RELAXED, __HIP_MEMORY_SCOPE_AGENT);
      asm volatile("s_waitcnt vmcnt(0)" ::: "memory");
      if (lane == 0)
        __hip_atomic_store(flown + s, t + 1, __ATOMIC_RELAXED, __HIP_MEMORY_SCOPE_AGENT);
      const int row = (g * 16 + (lane >> 2)) * 64 + t;
      *(uint4*)(hcat + (size_t)row * 1024 + colbase + (lane & 3) * 8) = v;
    }
  }
}

// ================= fused prep =================
struct CastJobs {
  const float* src[12];
  unsigned short* dst[12];
  long nreal4[12];
  long cum4[13];
  int n;
};

__global__ void cast_multi4(CastJobs J) {
  const long total = J.cum4[J.n];
  for (long i = (long)blockIdx.x * blockDim.x + threadIdx.x; i < total;
       i += (long)gridDim.x * blockDim.x) {
    int s = 0;
    while (i >= J.cum4[s + 1]) ++s;
    const long off = i - J.cum4[s];
    float4 v = {0.f, 0.f, 0.f, 0.f};
    if (off < J.nreal4[s]) v = ((const float4*)J.src[s])[off];
    ushort4 o;
    o.x = f2bf(v.x); o.y = f2bf(v.y); o.z = f2bf(v.z); o.w = f2bf(v.w);
    ((ushort4*)J.dst[s])[off] = o;
  }
}

// Fused small prep: perm_wih (vec8) + transp_cast + bias perms + concat + bias_comb.
__global__ void prep1(const float* __restrict__ Wv1, const float* __restrict__ Wv2,
                      const float* __restrict__ Wihl1, const float* __restrict__ Wihl2,
                      const float* __restrict__ b1, const float* __restrict__ b2,
                      const float* __restrict__ bih1, const float* __restrict__ bic1,
                      const float* __restrict__ bih2, const float* __restrict__ bic2,
                      const float* __restrict__ Wo1, const float* __restrict__ bv1,
                      const float* __restrict__ bo1,
                      const float* __restrict__ Wo2, const float* __restrict__ bv2,
                      const float* __restrict__ bo2,
                      unsigned short* __restrict__ WvT1, unsigned short* __restrict__ WvT2,
                      unsigned short* __restrict__ Wp1, unsigned short* __restrict__ Wp2,
                      float* __restrict__ bp1, float* __restrict__ bp2,
                      float* __restrict__ bcat,
                      float* __restrict__ bc1, float* __restrict__ bc2)
{
  const long NTOT = 924672;
  for (long id = (long)blockIdx.x * blockDim.x + threadIdx.x; id < NTOT;
       id += (long)gridDim.x * blockDim.x) {
    if (id < 131072) {              // perm W_ih1 by-8
      const int m = (int)(id >> 6), kb = (int)(id & 63) * 8;
      const float* sp = Wihl1 + (size_t)((m & 3) * 512 + (m >> 2)) * 512 + kb;
      unsigned short o[8];
#pragma unroll
      for (int e = 0; e < 8; ++e) o[e] = f2bf(sp[e]);
      *(uint4*)(Wp1 + (size_t)m * 512 + kb) = *(const uint4*)o;
    } else if (id < 393216) {       // perm W_ih2 by-8
      const long j = id - 131072;
      const int m = (int)(j >> 7), kb = (int)(j & 127) * 8;
      const float* sp = Wihl2 + (size_t)((m & 3) * 512 + (m >> 2)) * 1024 + kb;
      unsigned short o[8];
#pragma unroll
      for (int e = 0; e < 8; ++e) o[e] = f2bf(sp[e]);
      *(uint4*)(Wp2 + (size_t)m * 1024 + kb) = *(const uint4*)o;
    } else if (id < 917504) {       // transposed cast of Wv1/Wv2
      const long t = id - 393216;
      const int which = (int)(t >> 18);
      const int u = (int)(t & 262143), a = u >> 9, bb = u & 511;
      (which ? WvT2 : WvT1)[u] = f2bf((which ? Wv2 : Wv1)[(size_t)bb * 512 + a]);
    } else if (id < 921600) {       // bias perms
      const int t = (int)(id - 917504);
      if (t < 2048) bp1[t] = b1[(t & 3) * 512 + (t >> 2)];
      else { const int m = t - 2048; bp2[m] = b2[(m & 3) * 512 + (m >> 2)]; }
    } else if (id < 923648) {       // bcat concat
      const int i = (int)(id - 921600);
      const float* sarr[4] = {bih1, bic1, bih2, bic2};
      bcat[i] = sarr[i >> 9][i & 511];
    } else {                        // bc = Wo @ bv + bo (1024 rows)
      const int i = (int)(id - 923648);
      const float* Wo = (i >= 512) ? Wo2 : Wo1;
      const float* bv = (i >= 512) ? bv2 : bv1;
      const float* bo = (i >= 512) ? bo2 : bo1;
      float* bc = (i >= 512) ? bc2 : bc1;
      const int r = i & 511;
      float sacc = bo[r];
      for (int k = 0; k < 512; k += 4) {
        const float4 wv = *(const float4*)(Wo + (size_t)r * 512 + k);
        const float4 bb = *(const float4*)(bv + k);
        sacc += wv.x * bb.x + wv.y * bb.y + wv.z * bb.z + wv.w * bb.w;
      }
      bc[r] = sacc;
    }
  }
}

// gather + on-the-fly cast: x[row] = bf16(emb_f32[ix[row]])
__global__ void gather_rows(const int* __restrict__ ix, const float* __restrict__ emb,
                            unsigned short* __restrict__ x) {
  const int row = blockIdx.x;
  const int e = ix[row];
  const float4* s = (const float4*)(emb + (size_t)e * 512) + threadIdx.x * 2;
  const float4 a = s[0], b = s[1];
  unsigned short o[8] = {f2bf(a.x), f2bf(a.y), f2bf(a.z), f2bf(a.w),
                         f2bf(b.x), f2bf(b.y), f2bf(b.z), f2bf(b.w)};
  *(uint4*)(x + (size_t)row * 512 + threadIdx.x * 8) = *(const uint4*)o;
}

// Combined: reorder_wbf (blocks [0,512)) + beff2 (blocks [512,1024)) + blcat (rest)
__global__ void combo(const unsigned short* __restrict__ W, unsigned short* __restrict__ R,
                      const unsigned short* __restrict__ Wl, const float* __restrict__ blog,
                      const unsigned short* __restrict__ Wp2, const float* __restrict__ bp2,
                      const float* __restrict__ bc1, const float* __restrict__ bc2,
                      float* __restrict__ blcat, float* __restrict__ beff2) {
  const int lane = threadIdx.x & 63;
  if (blockIdx.x < 512) {
    const int id = blockIdx.x * 256 + threadIdx.x;  // 131072
    const int tid = id & 255, mi = (id >> 8) & 1, kk = (id >> 9) & 15, s = id >> 13;
    const int w = tid >> 6, ln = tid & 63, fr = ln & 15, kq = ln >> 4;
    const int row = s * 128 + w * 32 + mi * 16 + fr;
    const int col = kk * 32 + kq * 8;
    *((uint4*)R + id) = *(const uint4*)(W + (size_t)row * 512 + col);
  } else if (blockIdx.x < 1024) {
    const int m = (blockIdx.x - 512) * 4 + (threadIdx.x >> 6);
    const unsigned short* row = Wp2 + (size_t)m * 1024 + 512;
    float sum = 0.f;
    for (int k = lane; k < 512; k += 64) sum += bf2f(row[k]) * bc1[k];
#pragma unroll
    for (int mm = 32; mm; mm >>= 1) sum += __shfl_xor(sum, mm, 64);
    if (lane == 0) beff2[m] = bp2[m] + sum;
  } else {
    const int j = (blockIdx.x - 1024) * 4 + (threadIdx.x >> 6);  // < 10000
    const unsigned short* row = Wl + (size_t)j * 1536;
    float sum = 0.f;
    for (int k = lane; k < 512; k += 64) {
      sum += bf2f(row[512 + k]) * bc1[k];
      sum += bf2f(row[1024 + k]) * bc2[k];
    }
#pragma unroll
    for (int mm = 32; mm; mm >>= 1) sum += __shfl_xor(sum, mm, 64);
    if (lane == 0) blcat[j] = blog[j] + sum;
  }
}

// ================= host =================
extern "C" void kernel_launch(void* const* d_in, const int* in_sizes, int n_in,
                              void* d_out, int out_size, void* d_ws, size_t ws_size,
                              hipStream_t stream) {
  (void)in_sizes; (void)n_in; (void)out_size; (void)ws_size;
  const float* img    = (const float*)d_in[0];
  const int*   ix     = (const int*)d_in[1];
  const float* emb    = (const float*)d_in[2];
  const float* Wih1f  = (const float*)d_in[3];
  const float* bih1   = (const float*)d_in[4];
  const float* Wic1f  = (const float*)d_in[5];
  const float* bic1   = (const float*)d_in[6];
  const float* Wih2f  = (const float*)d_in[7];
  const float* bih2   = (const float*)d_in[8];
  const float* Wic2f  = (const float*)d_in[9];
  const float* bic2   = (const float*)d_in[10];
  const float* Wihl1  = (const float*)d_in[11];
  const float* Whhl1  = (const float*)d_in[12];
  const float* b1     = (const float*)d_in[13];
  const float* Wihl2  = (const float*)d_in[14];
  const float* Whhl2  = (const float*)d_in[15];
  const float* b2     = (const float*)d_in[16];
  const float* Wv1    = (const float*)d_in[17];
  const float* bv1    = (const float*)d_in[18];
  const float* Wo1    = (const float*)d_in[19];
  const float* bo1    = (const float*)d_in[20];
  const float* Wv2    = (const float*)d_in[21];
  const float* bv2    = (const float*)d_in[22];
  const float* Wo2    = (const float*)d_in[23];
  const float* bo2    = (const float*)d_in[24];
  const float* Wlog   = (const float*)d_in[25];
  const float* blog   = (const float*)d_in[26];
  float* out = (float*)d_out;

  char* p = (char*)d_ws;
  auto al = [&](size_t bytes) { char* r = p; p += (bytes + 255) & ~(size_t)255; return r; };
  unsigned short* Wp1    = (unsigned short*)al((size_t)2048 * 512 * 2);
  unsigned short* Whh1_b = (unsigned short*)al((size_t)2048 * 512 * 2);
  unsigned short* Wp2    = (unsigned short*)al((size_t)2048 * 1024 * 2);
  unsigned short* Whh2_b = (unsigned short*)al((size_t)2048 * 512 * 2);
  unsigned short* WvT1   = (unsigned short*)al((size_t)512 * 512 * 2);
  unsigned short* Wo1_b  = (unsigned short*)al((size_t)512 * 512 * 2);
  unsigned short* WvT2   = (unsigned short*)al((size_t)512 * 512 * 2);
  unsigned short* Wo2_b  = (unsigned short*)al((size_t)512 * 512 * 2);
  unsigned short* Wc1T   = (unsigned short*)al((size_t)512 * 512 * 2);
  unsigned short* Wc2T   = (unsigned short*)al((size_t)512 * 512 * 2);
  unsigned short* Wlog_b = (unsigned short*)al((size_t)10240 * 1536 * 2);
  unsigned short* Wcat   = (unsigned short*)al((size_t)10240 * 1024 * 2);
  unsigned short* Weff2  = (unsigned short*)al((size_t)2048 * 512 * 2);
  unsigned short* Weff2r = (unsigned short*)al((size_t)2048 * 512 * 2);
  unsigned short* Wh1i_b = (unsigned short*)al((size_t)512 * 2048 * 2);
  unsigned short* Wc1i_b = (unsigned short*)al((size_t)512 * 2048 * 2);
  unsigned short* Wh2i_b = (unsigned short*)al((size_t)512 * 2048 * 2);
  unsigned short* Wc2i_b = (unsigned short*)al((size_t)512 * 2048 * 2);
  unsigned short* img_b  = (unsigned short*)al((size_t)128 * 2048 * 2);
  unsigned short* x_b    = (unsigned short*)al((size_t)8192 * 512 * 2);
  float*          xpr    = (float*)al((size_t)8192 * 2048 * 4);
  unsigned short* hcat   = (unsigned short*)al((size_t)8192 * 1024 * 2);
  unsigned short* hx1    = (unsigned short*)al((size_t)64 * 128 * 512 * 2);
  unsigned short* hx2    = (unsigned short*)al((size_t)64 * 128 * 512 * 2);
  unsigned short* h01    = (unsigned short*)al((size_t)128 * 512 * 2);
  unsigned short* h02    = (unsigned short*)al((size_t)128 * 512 * 2);
  float*          c1st   = (float*)al((size_t)128 * 512 * 4);
  float*          c2st   = (float*)al((size_t)128 * 512 * 4);
  float*          bcat   = (float*)al((size_t)2048 * 4);
  float*          bp1    = (float*)al((size_t)2048 * 4);
  float*          bp2    = (float*)al((size_t)2048 * 4);
  float*          bc1    = (float*)al((size_t)512 * 4);
  float*          bc2    = (float*)al((size_t)512 * 4);
  float*          beff2  = (float*)al((size_t)2048 * 4);
  float*          blcat  = (float*)al((size_t)10240 * 4);
  int*            flags  = (int*)al(2048);

  hipMemsetAsync(flags, 0, 2048, stream);

  // ---- casts (vec4; emb handled by gather_rows) ----
  CastJobs J = {};
  auto addjob = [&](const float* s, unsigned short* d, long nreal, long ntot) {
    J.src[J.n] = s; J.dst[J.n] = d; J.nreal4[J.n] = nreal / 4;
    J.cum4[J.n + 1] = J.cum4[J.n] + ntot / 4; ++J.n;
  };
  addjob(img,   img_b,  (long)128 * 2048,   (long)128 * 2048);
  addjob(Whhl1, Whh1_b, (long)2048 * 512,   (long)2048 * 512);
  addjob(Whhl2, Whh2_b, (long)2048 * 512,   (long)2048 * 512);
  addjob(Wo1,   Wo1_b,  (long)512 * 512,    (long)512 * 512);
  addjob(Wo2,   Wo2_b,  (long)512 * 512,    (long)512 * 512);
  addjob(Wih1f, Wh1i_b, (long)512 * 2048,   (long)512 * 2048);
  addjob(Wic1f, Wc1i_b, (long)512 * 2048,   (long)512 * 2048);
  addjob(Wih2f, Wh2i_b, (long)512 * 2048,   (long)512 * 2048);
  addjob(Wic2f, Wc2i_b, (long)512 * 2048,   (long)512 * 2048);
  addjob(Wlog,  Wlog_b, (long)10000 * 1536, (long)10240 * 1536);
  cast_multi4<<<2048, 256, 0, stream>>>(J);

  prep1<<<1024, 256, 0, stream>>>(Wv1, Wv2, Wihl1, Wihl2, b1, b2,
                                  bih1, bic1, bih2, bic2,
                                  Wo1, bv1, bo1, Wo2, bv2, bo2,
                                  WvT1, WvT2, Wp1, Wp2, bp1, bp2, bcat, bc1, bc2);

  gather_rows<<<8192, 64, 0, stream>>>(ix, emb, x_b);

  // ---- batch A: xp1 (MODE2) | WcT1 | WcT2 (MODE1) | init (MODE3) ----
  {
    GJobs B = {};
    B.j[0] = {Wp1, x_b, xpr, nullptr, nullptr, nullptr, bp1,
              512, 512, 0, 0, 512, 8192, 16, 2, 1024, 0};
    B.j[1] = {WvT1, Wo1_b, Wc1T, nullptr, nullptr, nullptr, nullptr,
              512, 512, 512, 0, 512, 512, 4, 1, 1040, 0};
    B.j[2] = {WvT2, Wo2_b, Wc2T, nullptr, nullptr, nullptr, nullptr,
              512, 512, 512, 0, 512, 512, 4, 1, 1056, 0};
    B.j[3] = {img_b, Wh1i_b, h01, c1st, h02, c2st, bcat,
              2048, 2048, 0, 0, 2048, 2048, 1, 3, 1072, 0};
    gemm_batch<<<1072, 256, 0, stream>>>(B);
  }

  // ---- batch B: Wcat-a (MODE4) | Wcat-b (MODE1) | Weff2 fold (MODE4) ----
  {
    GJobs B = {};
    B.j[0] = {Wlog_b + 1024, Wc2T, Wcat, Wlog_b, nullptr, nullptr, nullptr,
              1536, 512, 1024, 1536, 512, 512, 80, 4, 320, 0};
    B.j[1] = {Wlog_b + 512, Wc1T, Wcat + 512, nullptr, nullptr, nullptr, nullptr,
              1536, 512, 1024, 0, 512, 512, 80, 1, 640, 0};
    B.j[2] = {Wp2 + 512, Wc1T, Weff2, Wp2, nullptr, nullptr, nullptr,
              1024, 512, 512, 1024, 512, 512, 16, 4, 704, 0};
    gemm_batch<<<704, 256, 0, stream>>>(B);
  }

  // ---- combo: reorder Weff2 + beff2 + blcat ----
  combo<<<3524, 256, 0, stream>>>(Weff2, Weff2r, Wlog_b, blog, Wp2, bp2,
                                  bc1, bc2, blcat, beff2);

  // ---- both LSTMs, fused & pipelined (R13-exact) ----
  lstm_fused<<<256, 256, 0, stream>>>(
      Whh1_b, Whh2_b, Weff2r, h01, h02, c1st, c2st, xpr, beff2, hx1, hx2, hcat, flags);

  // ---- logits = hcat @ Wcat^T + blcat (coalesced LDS epilogue) ----
  gemm256<<<dim3(32, 40), 512, 0, stream>>>(
      hcat, 1024, Wcat, 1024, out, 10000, blcat, 1024, 10000);
}

// Round 16
// 766.976 us; speedup vs baseline: 2.0858x; 2.0858x over previous
//
#include <hip/hip_runtime.h>
#include <stdint.h>

#define DEV __device__ __forceinline__

typedef short bf16x8 __attribute__((ext_vector_type(8)));
typedef float f32x4 __attribute__((ext_vector_type(4)));

DEV unsigned short f2bf(float f) {
  union { float f; uint32_t u; } v; v.f = f;
  return (unsigned short)((v.u + 0x7fffu + ((v.u >> 16) & 1u)) >> 16);
}
DEV float bf2f(unsigned short u) {
  union { uint32_t u; float f; } v; v.u = (uint32_t)u << 16; return v.f;
}

DEV float fsig(float x) { return 1.f / (1.f + __expf(-x)); }
DEV float ftanh(float x) { float e = __expf(2.f * x); return 1.f - 2.f / (e + 1.f); }

DEV void gload16(const void* g, void* lds) {
  __builtin_amdgcn_global_load_lds(
      (const __attribute__((address_space(1))) int*)(uintptr_t)g,
      (__attribute__((address_space(3))) int*)(uintptr_t)lds, 16, 0, 0);
}

// ================= batched NT GEMM: up to 4 jobs per launch =================
struct GJob {
  const unsigned short* A; const unsigned short* B;
  void *P0, *P1, *P2, *P3;
  const float* bias;
  int lda, ldb, ldc, ldc2, K, Nreal, gx, mode, wg_end, pad;
};
struct GJobs { GJob j[4]; };

__global__ __launch_bounds__(256) void gemm_batch(GJobs JB) {
  int ji = 0;
  while ((int)blockIdx.x >= JB.j[ji].wg_end) ++ji;
  const GJob J = JB.j[ji];
  const int wg = blockIdx.x - (ji ? JB.j[ji - 1].wg_end : 0);

  __shared__ alignas(16) unsigned short Asm[128 * 32];
  __shared__ alignas(16) unsigned short Bsm[128 * 32];
  const int tid = threadIdx.x;
  const int wave = tid >> 6, lane = tid & 63;
  const int m0 = (wg % J.gx) * 128, n0 = (wg / J.gx) * 128;
  const int wr = wave >> 1, wc = wave & 1;

  f32x4 acc[4][4] = {};

  const int q0 = tid, q1 = tid + 256;
  const unsigned short* Ag0 = J.A + (size_t)(m0 + (q0 >> 2)) * J.lda + (q0 & 3) * 8;
  const unsigned short* Ag1 = J.A + (size_t)(m0 + (q1 >> 2)) * J.lda + (q1 & 3) * 8;
  const unsigned short* Bg0 = J.B + (size_t)(n0 + (q0 >> 2)) * J.ldb + (q0 & 3) * 8;
  const unsigned short* Bg1 = J.B + (size_t)(n0 + (q1 >> 2)) * J.ldb + (q1 & 3) * 8;
  char* As0 = (char*)Asm + wave * 1024;  char* As1 = As0 + 4096;
  char* Bs0 = (char*)Bsm + wave * 1024;  char* Bs1 = Bs0 + 4096;

  const int ra = wr * 64 + (lane & 15);
  const int rb = wc * 64 + (lane & 15);
  const int kb = (lane >> 4) * 16;

  for (int k0 = 0; k0 < J.K; k0 += 32) {
    gload16(Ag0 + k0, As0);
    gload16(Ag1 + k0, As1);
    gload16(Bg0 + k0, Bs0);
    gload16(Bg1 + k0, Bs1);
    __syncthreads();
    bf16x8 af[4], bfr[4];
#pragma unroll
    for (int i = 0; i < 4; ++i)
      af[i] = *(const bf16x8*)((const char*)Asm + (ra + i * 16) * 64 + kb);
#pragma unroll
    for (int i = 0; i < 4; ++i)
      bfr[i] = *(const bf16x8*)((const char*)Bsm + (rb + i * 16) * 64 + kb);
#pragma unroll
    for (int mi = 0; mi < 4; ++mi)
#pragma unroll
      for (int ni = 0; ni < 4; ++ni)
        acc[mi][ni] = __builtin_amdgcn_mfma_f32_16x16x32_bf16(af[mi], bfr[ni], acc[mi][ni], 0, 0, 0);
    __syncthreads();
  }

  const int row0 = m0 + wr * 64 + (lane >> 4) * 4;
  const int col0 = n0 + wc * 64 + (lane & 15);

  if (J.mode == 2) {
#pragma unroll
    for (int mi = 0; mi < 4; ++mi) {
      const int rowb = row0 + mi * 16;       // multiple of 4
      const int dd = rowb >> 2;
      const float4 b4 = *(const float4*)&J.bias[rowb];
#pragma unroll
      for (int ni = 0; ni < 4; ++ni) {
        const int col = col0 + ni * 16;
        const int tt = col & 63, bb = col >> 6;
        float4 v;
        v.x = acc[mi][ni][0] + b4.x;
        v.y = acc[mi][ni][1] + b4.y;
        v.z = acc[mi][ni][2] + b4.z;
        v.w = acc[mi][ni][3] + b4.w;
        const int wgid = (bb >> 4) * 16 + (dd >> 5);
        const int ww = (dd >> 3) & 3, mi2 = (dd >> 2) & 1, ln = (dd & 3) * 16 + (bb & 15);
        ((float4*)J.P0)[((((size_t)tt * 128 + wgid) * 4 + ww) * 2 + mi2) * 64 + ln] = v;
      }
    }
    return;
  }

#pragma unroll
  for (int mi = 0; mi < 4; ++mi) {
#pragma unroll
    for (int ni = 0; ni < 4; ++ni) {
      const int col = col0 + ni * 16;
      if (col >= J.Nreal) continue;
      const float bs = J.bias ? J.bias[col] : 0.f;
#pragma unroll
      for (int rr = 0; rr < 4; ++rr) {
        const int row = row0 + mi * 16 + rr;
        const float v = acc[mi][ni][rr] + bs;
        if (J.mode == 1) {
          ((unsigned short*)J.P0)[(size_t)row * J.ldc + col] = f2bf(v);
          if (J.P1) ((unsigned short*)J.P1)[(size_t)row * J.ldc2 + col] = f2bf(v);
        } else if (J.mode == 4) {
          const unsigned short ad = ((const unsigned short*)J.P1)[(size_t)row * J.ldc2 + col];
          ((unsigned short*)J.P0)[(size_t)row * J.ldc + col] = f2bf(v + bf2f(ad));
        } else {  // mode 3
          const int seg = col >> 9, cc = col & 511;
          if (seg == 0)      ((unsigned short*)J.P0)[(size_t)row * 512 + cc] = f2bf(v);
          else if (seg == 1) ((float*)J.P1)[(size_t)row * 512 + cc] = v;
          else if (seg == 2) ((unsigned short*)J.P2)[(size_t)row * 512 + cc] = f2bf(v);
          else               ((float*)J.P3)[(size_t)row * 512 + cc] = v;
        }
      }
    }
  }
}

// ============ 256x256 tile GEMM, BK=64, counted vmcnt pipeline, NT C-stores ============
// R14-exact epilogue (per-lane 4B NT stores: each wave store covers 4 full 64B lines
// -- already line-efficient; R15's LDS-transpose variant caused partial-line RMW
// amplification, WRITE_SIZE x2.2, and regressed 5.6x. Reverted.)
__global__ __launch_bounds__(512, 2) void gemm256(
    const unsigned short* __restrict__ A, int lda,
    const unsigned short* __restrict__ B, int ldb,
    float* __restrict__ C, int ldc,
    const float* __restrict__ bias, int K, int Nreal)
{
  __shared__ alignas(16) unsigned short Lds[2][2][16384];
  const int tid = threadIdx.x;
  const int wave = tid >> 6, lane = tid & 63;
  const int fr = lane & 15, kq = lane >> 4;

  const int gx = gridDim.x;
  const int lin = blockIdx.y * gx + blockIdx.x;
  const int nwg = gx * gridDim.y;
  const int q8 = nwg >> 3, r8 = nwg & 7;
  const int xcd = lin & 7, i2 = lin >> 3;
  const int wg = (xcd < r8 ? xcd * (q8 + 1) : r8 * (q8 + 1) + (xcd - r8) * q8) + i2;
  const int m0 = (wg % gx) * 256, n0 = (wg / gx) * 256;

  const int wr = wave >> 2, wc = wave & 3;

  const unsigned short* srcA[4];
  const unsigned short* srcB[4];
  int dstO[4];
#pragma unroll
  for (int s = 0; s < 4; ++s) {
    const int c = tid + s * 512;
    const int row = c >> 3, qp = (c & 7) ^ (row & 7);
    srcA[s] = A + (size_t)(m0 + row) * lda + qp * 8;
    srcB[s] = B + (size_t)(n0 + row) * ldb + qp * 8;
    dstO[s] = (wave * 64 + s * 512) * 16;
  }

  const int NT = K >> 6;
#define STAGE256(kt, buf)                                            \
  {                                                                  \
    _Pragma("unroll")                                                \
    for (int s = 0; s < 4; ++s)                                      \
      gload16(srcA[s] + (kt) * 64, (char*)&Lds[buf][0][0] + dstO[s]);\
    _Pragma("unroll")                                                \
    for (int s = 0; s < 4; ++s)                                      \
      gload16(srcB[s] + (kt) * 64, (char*)&Lds[buf][1][0] + dstO[s]);\
  }
  STAGE256(0, 0);
  STAGE256(1, 1);

  f32x4 acc[8][4] = {};
  const int slot0 = (kq ^ (fr & 7)) * 16;

  for (int kt = 0; kt < NT; ++kt) {
    asm volatile("s_waitcnt vmcnt(8)" ::: "memory");
    __builtin_amdgcn_sched_barrier(0);
    __builtin_amdgcn_s_barrier();
    __builtin_amdgcn_sched_barrier(0);
    const char* bufA = (const char*)&Lds[kt & 1][0][0];
    const char* bufB = (const char*)&Lds[kt & 1][1][0];
    bf16x8 Bf[4][2];
#pragma unroll
    for (int n = 0; n < 4; ++n) {
      const char* bb = bufB + (wc * 64 + n * 16 + fr) * 128;
      Bf[n][0] = *(const bf16x8*)(bb + slot0);
      Bf[n][1] = *(const bf16x8*)(bb + (slot0 ^ 64));
    }
#pragma unroll
    for (int q = 0; q < 4; ++q) {
      bf16x8 Af[2][2];
#pragma unroll
      for (int m2 = 0; m2 < 2; ++m2) {
        const char* ab = bufA + (wr * 128 + q * 32 + m2 * 16 + fr) * 128;
        Af[m2][0] = *(const bf16x8*)(ab + slot0);
        Af[m2][1] = *(const bf16x8*)(ab + (slot0 ^ 64));
      }
      __builtin_amdgcn_s_setprio(1);
#pragma unroll
      for (int m2 = 0; m2 < 2; ++m2)
#pragma unroll
        for (int n = 0; n < 4; ++n) {
          acc[q * 2 + m2][n] = __builtin_amdgcn_mfma_f32_16x16x32_bf16(
              Af[m2][0], Bf[n][0], acc[q * 2 + m2][n], 0, 0, 0);
          acc[q * 2 + m2][n] = __builtin_amdgcn_mfma_f32_16x16x32_bf16(
              Af[m2][1], Bf[n][1], acc[q * 2 + m2][n], 0, 0, 0);
        }
      __builtin_amdgcn_s_setprio(0);
    }
    __builtin_amdgcn_sched_barrier(0);
    __builtin_amdgcn_s_barrier();
    __builtin_amdgcn_sched_barrier(0);
    const int kn = (kt + 2 < NT) ? kt + 2 : 0;
    STAGE256(kn, kt & 1);
  }

#pragma unroll
  for (int mf = 0; mf < 8; ++mf) {
    const int row = m0 + wr * 128 + mf * 16 + kq * 4;
#pragma unroll
    for (int n = 0; n < 4; ++n) {
      const int col = n0 + wc * 64 + n * 16 + fr;
      if (col < Nreal) {
        const float bs = bias[col];
#pragma unroll
        for (int rr = 0; rr < 4; ++rr)
          __builtin_nontemporal_store(acc[mf][n][rr] + bs,
                                      &C[(size_t)(row + rr) * ldc + col]);
      }
    }
  }
#undef STAGE256
}

// ================= fused persistent LSTM1+LSTM2 (256 WGs, 1/CU) =================
// R13-exact (AGENT-scope LLC exchange, split phase B, late fl2 poll).
__global__ __launch_bounds__(256, 1) void lstm_fused(
    const unsigned short* __restrict__ Whh1, const unsigned short* __restrict__ Whh2,
    const unsigned short* __restrict__ Weff2r,  // [16 s][16 kk][2 mi][256 tid][8] bf16
    const unsigned short* __restrict__ h01, const unsigned short* __restrict__ h02,
    const float* __restrict__ c1st, const float* __restrict__ c2st,
    const float* __restrict__ xpr,              // [64][128][4][2][64][4] f32
    const float* __restrict__ beff2,            // [2048] gate-interleaved
    unsigned short* __restrict__ hx1, unsigned short* __restrict__ hx2,
    unsigned short* __restrict__ hcat,          // [8192][1024]: [h2s | h1s]
    int* __restrict__ flags)                    // [2][8][16] ints
{
  __shared__ unsigned short Wsm[8][128][64];
  __shared__ uint32_t Hst[16][16];              // packed h staging (1KB)
  const int tid = threadIdx.x;
  const bool role2 = blockIdx.x >= 128;
  const int wg = role2 ? blockIdx.x - 128 : blockIdx.x;
  const int g = wg >> 4, s = wg & 15;
  const int w = tid >> 6, lane = tid & 63, fr = lane & 15, kq = lane >> 4;

  // ---- stage Whh slice into LDS (slot = chunk ^ (m&7)) ----
  {
    const unsigned short* Whh = role2 ? Whh2 : Whh1;
    const int m = tid >> 1;
    const int row = (m & 3) * 512 + s * 32 + (m >> 2);
    const unsigned short* src = Whh + (size_t)row * 512 + (tid & 1) * 256;
#pragma unroll 4
    for (int cc = 0; cc < 32; ++cc) {
      const int k = (tid & 1) * 256 + cc * 8;
      uint4 v = *(const uint4*)(src + cc * 8);
      const int kblk = k >> 6, c = (k & 63) >> 3, sl = c ^ (m & 7);
      *(uint4*)((char*)&Wsm[kblk][m][0] + sl * 16) = v;
    }
  }

  const int b = g * 16 + fr;
  const int d0 = s * 32 + w * 8 + kq;
  const float* c0 = role2 ? c2st : c1st;
  float c_r[2];
  c_r[0] = c0[b * 512 + d0];
  c_r[1] = c0[b * 512 + d0 + 4];
  __syncthreads();

  int* fl1 = flags + g * 16;
  int* fl2 = flags + 128 + g * 16;
  int* flown = role2 ? fl2 : fl1;
  unsigned short* hxown = role2 ? hx2 : hx1;
  const unsigned short* hinit = role2 ? h02 : h01;
  const int colbase = (role2 ? 0 : 512) + s * 32;
  const float4* xv = (const float4*)xpr + ((size_t)(wg * 4 + w) * 2) * 64 + lane;
  float4 be0 = {0, 0, 0, 0}, be1 = {0, 0, 0, 0};
  if (role2) {
    be0 = *(const float4*)(beff2 + s * 128 + w * 32 + kq * 4);
    be1 = *(const float4*)(beff2 + s * 128 + w * 32 + 16 + kq * 4);
  }
  const size_t hxg = (size_t)g * 8192;           // per-t region offset for group

  for (int t = 0; t < 64; ++t) {
    f32x4 acc[2] = {};
    float4 xg0, xg1;

    if (!role2) {
      xg0 = xv[(size_t)t * 65536];               // HBM prefetch before poll
      xg1 = xv[(size_t)t * 65536 + 64];
      // ---- poll: own group's h1(t-1) posted ----
      if (t) {
        if (w == 1) {
          for (;;) {
            bool ok = true;
            if (lane < 16)
              ok = __hip_atomic_load(fl1 + lane, __ATOMIC_RELAXED,
                                     __HIP_MEMORY_SCOPE_AGENT) >= t;
            if (__all(ok)) break;
            __builtin_amdgcn_s_sleep(1);
          }
        }
        __syncthreads();
      }
      // ---- own-h fragments ----
      bf16x8 hf[16];
      if (t == 0) {
#pragma unroll
        for (int kk = 0; kk < 16; ++kk)
          hf[kk] = *(const bf16x8*)(hinit + (size_t)b * 512 + kk * 32 + kq * 8);
      } else {
        const unsigned short* hb = hx1 + (size_t)(t - 1) * 65536 + hxg + fr * 32 + kq * 8;
#pragma unroll
        for (int kk = 0; kk < 16; ++kk)
          hf[kk] = *(const bf16x8*)(hb + kk * 512);
      }
      // ---- phase A: Whh1 @ h1 (LDS) ----
#pragma unroll
      for (int kk = 0; kk < 16; ++kk) {
        const int kblk = kk >> 1, cbase = (kk & 1) * 4 + kq;
#pragma unroll
        for (int mi = 0; mi < 2; ++mi) {
          const int m = w * 32 + mi * 16 + fr;
          const int sl = cbase ^ (m & 7);
          const bf16x8 af = *(const bf16x8*)((const char*)&Wsm[kblk][m][0] + sl * 16);
          acc[mi] = __builtin_amdgcn_mfma_f32_16x16x32_bf16(af, hf[kk], acc[mi], 0, 0, 0);
        }
      }
    } else {
      xg0 = be0; xg1 = be1;
      // ---- poll: h1(t) posted (role1 runs ahead -> usually instant) ----
      if (w == 1) {
        for (;;) {
          bool ok = true;
          if (lane < 16)
            ok = __hip_atomic_load(fl1 + lane, __ATOMIC_RELAXED,
                                   __HIP_MEMORY_SCOPE_AGENT) >= t + 1;
          if (__all(ok)) break;
          __builtin_amdgcn_s_sleep(1);
        }
      }
      __syncthreads();
      const unsigned short* h1b = hx1 + (size_t)t * 65536 + hxg + fr * 32 + kq * 8;
      bf16x8 hf1[16];
#pragma unroll
      for (int kk = 0; kk < 16; ++kk)
        hf1[kk] = *(const bf16x8*)(h1b + kk * 512);
      const bf16x8* wr = (const bf16x8*)Weff2r + (size_t)s * 32 * 256 + tid;
      // ---- phase B first half (kk 0..7) ----
#pragma unroll
      for (int kk = 0; kk < 8; ++kk) {
#pragma unroll
        for (int mi = 0; mi < 2; ++mi)
          acc[mi] = __builtin_amdgcn_mfma_f32_16x16x32_bf16(
              wr[(kk * 2 + mi) * 256], hf1[kk], acc[mi], 0, 0, 0);
      }
      // ---- late poll of own cohort; then ISSUE h2 loads ----
      if (t) {
        if (w == 1) {
          for (;;) {
            bool ok = true;
            if (lane < 16)
              ok = __hip_atomic_load(fl2 + lane, __ATOMIC_RELAXED,
                                     __HIP_MEMORY_SCOPE_AGENT) >= t;
            if (__all(ok)) break;
            __builtin_amdgcn_s_sleep(1);
          }
        }
        __syncthreads();
      }
      bf16x8 hf2[16];
      if (t == 0) {
#pragma unroll
        for (int kk = 0; kk < 16; ++kk)
          hf2[kk] = *(const bf16x8*)(hinit + (size_t)b * 512 + kk * 32 + kq * 8);
      } else {
        const unsigned short* hb = hx2 + (size_t)(t - 1) * 65536 + hxg + fr * 32 + kq * 8;
#pragma unroll
        for (int kk = 0; kk < 16; ++kk)
          hf2[kk] = *(const bf16x8*)(hb + kk * 512);
      }
      // ---- phase B second half (kk 8..15): covers the h2 LLC fetch ----
#pragma unroll
      for (int kk = 8; kk < 16; ++kk) {
#pragma unroll
        for (int mi = 0; mi < 2; ++mi)
          acc[mi] = __builtin_amdgcn_mfma_f32_16x16x32_bf16(
              wr[(kk * 2 + mi) * 256], hf1[kk], acc[mi], 0, 0, 0);
      }
      // ---- phase A: Whh2 @ h2 (LDS), accumulate ----
#pragma unroll
      for (int kk = 0; kk < 16; ++kk) {
        const int kblk = kk >> 1, cbase = (kk & 1) * 4 + kq;
#pragma unroll
        for (int mi = 0; mi < 2; ++mi) {
          const int m = w * 32 + mi * 16 + fr;
          const int sl = cbase ^ (m & 7);
          const bf16x8 af = *(const bf16x8*)((const char*)&Wsm[kblk][m][0] + sl * 16);
          acc[mi] = __builtin_amdgcn_mfma_f32_16x16x32_bf16(af, hf2[kk], acc[mi], 0, 0, 0);
        }
      }
    }

    // ---- gates (lane-local) ----
    unsigned short hn[2];
#pragma unroll
    for (int mi = 0; mi < 2; ++mi) {
      const float4 xg = mi ? xg1 : xg0;
      const float iv = acc[mi][0] + xg.x;
      const float fv = acc[mi][1] + xg.y;
      const float gv = acc[mi][2] + xg.z;
      const float ov = acc[mi][3] + xg.w;
      const float c = fsig(fv) * c_r[mi] + fsig(iv) * ftanh(gv);
      c_r[mi] = c;
      hn[mi] = f2bf(fsig(ov) * ftanh(c));
    }

    // ---- pack to d-linear order: shfl + perm, stage in LDS ----
    const uint32_t pk = (uint32_t)hn[0] | ((uint32_t)hn[1] << 16);   // (d, d+4)
    const uint32_t y = (uint32_t)__shfl_xor((int)pk, 16);            // partner kq^1
    const uint32_t word = (kq & 1) ? __builtin_amdgcn_perm(pk, y, 0x07060302)
                                   : __builtin_amdgcn_perm(y, pk, 0x05040100);
    Hst[fr][w * 4 + ((kq & 1) ? 2 + (kq >> 1) : (kq >> 1))] = word;
    __syncthreads();

    // ---- wave 0: wide exchange stores (AGENT) + flag + hcat ----
    if (w == 0) {
      const uint4 v = *(const uint4*)&Hst[lane >> 2][(lane & 3) * 4];
      unsigned short* dst = hxown + (size_t)t * 65536 + hxg + s * 512 + lane * 8;
      __hip_atomic_store((unsigned long long*)dst, ((const unsigned long long*)&v)[0],
                         __ATOMIC_RELAXED, __HIP_MEMORY_SCOPE_AGENT);
      __hip_atomic_store((unsigned long long*)(dst + 4), ((const unsigned long long*)&v)[1],
                         __ATOMIC_RELAXED, __HIP_MEMORY_SCOPE_AGENT);
      asm volatile("s_waitcnt vmcnt(0)" ::: "memory");
      if (lane == 0)
        __hip_atomic_store(flown + s, t + 1, __ATOMIC_RELAXED, __HIP_MEMORY_SCOPE_AGENT);
      const int row = (g * 16 + (lane >> 2)) * 64 + t;
      *(uint4*)(hcat + (size_t)row * 1024 + colbase + (lane & 3) * 8) = v;
    }
  }
}

// ================= fused prep =================
struct CastJobs {
  const float* src[12];
  unsigned short* dst[12];
  long nreal4[12];
  long cum4[13];
  int n;
};

__global__ void cast_multi4(CastJobs J) {
  const long total = J.cum4[J.n];
  for (long i = (long)blockIdx.x * blockDim.x + threadIdx.x; i < total;
       i += (long)gridDim.x * blockDim.x) {
    int s = 0;
    while (i >= J.cum4[s + 1]) ++s;
    const long off = i - J.cum4[s];
    float4 v = {0.f, 0.f, 0.f, 0.f};
    if (off < J.nreal4[s]) v = ((const float4*)J.src[s])[off];
    ushort4 o;
    o.x = f2bf(v.x); o.y = f2bf(v.y); o.z = f2bf(v.z); o.w = f2bf(v.w);
    ((ushort4*)J.dst[s])[off] = o;
  }
}

// Fused small prep: perm_wih (vec8) + transp_cast + bias perms + concat + bias_comb.
__global__ void prep1(const float* __restrict__ Wv1, const float* __restrict__ Wv2,
                      const float* __restrict__ Wihl1, const float* __restrict__ Wihl2,
                      const float* __restrict__ b1, const float* __restrict__ b2,
                      const float* __restrict__ bih1, const float* __restrict__ bic1,
                      const float* __restrict__ bih2, const float* __restrict__ bic2,
                      const float* __restrict__ Wo1, const float* __restrict__ bv1,
                      const float* __restrict__ bo1,
                      const float* __restrict__ Wo2, const float* __restrict__ bv2,
                      const float* __restrict__ bo2,
                      unsigned short* __restrict__ WvT1, unsigned short* __restrict__ WvT2,
                      unsigned short* __restrict__ Wp1, unsigned short* __restrict__ Wp2,
                      float* __restrict__ bp1, float* __restrict__ bp2,
                      float* __restrict__ bcat,
                      float* __restrict__ bc1, float* __restrict__ bc2)
{
  const long NTOT = 924672;
  for (long id = (long)blockIdx.x * blockDim.x + threadIdx.x; id < NTOT;
       id += (long)gridDim.x * blockDim.x) {
    if (id < 131072) {              // perm W_ih1 by-8
      const int m = (int)(id >> 6), kb = (int)(id & 63) * 8;
      const float* sp = Wihl1 + (size_t)((m & 3) * 512 + (m >> 2)) * 512 + kb;
      unsigned short o[8];
#pragma unroll
      for (int e = 0; e < 8; ++e) o[e] = f2bf(sp[e]);
      *(uint4*)(Wp1 + (size_t)m * 512 + kb) = *(const uint4*)o;
    } else if (id < 393216) {       // perm W_ih2 by-8
      const long j = id - 131072;
      const int m = (int)(j >> 7), kb = (int)(j & 127) * 8;
      const float* sp = Wihl2 + (size_t)((m & 3) * 512 + (m >> 2)) * 1024 + kb;
      unsigned short o[8];
#pragma unroll
      for (int e = 0; e < 8; ++e) o[e] = f2bf(sp[e]);
      *(uint4*)(Wp2 + (size_t)m * 1024 + kb) = *(const uint4*)o;
    } else if (id < 917504) {       // transposed cast of Wv1/Wv2
      const long t = id - 393216;
      const int which = (int)(t >> 18);
      const int u = (int)(t & 262143), a = u >> 9, bb = u & 511;
      (which ? WvT2 : WvT1)[u] = f2bf((which ? Wv2 : Wv1)[(size_t)bb * 512 + a]);
    } else if (id < 921600) {       // bias perms
      const int t = (int)(id - 917504);
      if (t < 2048) bp1[t] = b1[(t & 3) * 512 + (t >> 2)];
      else { const int m = t - 2048; bp2[m] = b2[(m & 3) * 512 + (m >> 2)]; }
    } else if (id < 923648) {       // bcat concat
      const int i = (int)(id - 921600);
      const float* sarr[4] = {bih1, bic1, bih2, bic2};
      bcat[i] = sarr[i >> 9][i & 511];
    } else {                        // bc = Wo @ bv + bo (1024 rows)
      const int i = (int)(id - 923648);
      const float* Wo = (i >= 512) ? Wo2 : Wo1;
      const float* bv = (i >= 512) ? bv2 : bv1;
      const float* bo = (i >= 512) ? bo2 : bo1;
      float* bc = (i >= 512) ? bc2 : bc1;
      const int r = i & 511;
      float sacc = bo[r];
      for (int k = 0; k < 512; k += 4) {
        const float4 wv = *(const float4*)(Wo + (size_t)r * 512 + k);
        const float4 bb = *(const float4*)(bv + k);
        sacc += wv.x * bb.x + wv.y * bb.y + wv.z * bb.z + wv.w * bb.w;
      }
      bc[r] = sacc;
    }
  }
}

// gather + on-the-fly cast: x[row] = bf16(emb_f32[ix[row]])
__global__ void gather_rows(const int* __restrict__ ix, const float* __restrict__ emb,
                            unsigned short* __restrict__ x) {
  const int row = blockIdx.x;
  const int e = ix[row];
  const float4* s = (const float4*)(emb + (size_t)e * 512) + threadIdx.x * 2;
  const float4 a = s[0], b = s[1];
  unsigned short o[8] = {f2bf(a.x), f2bf(a.y), f2bf(a.z), f2bf(a.w),
                         f2bf(b.x), f2bf(b.y), f2bf(b.z), f2bf(b.w)};
  *(uint4*)(x + (size_t)row * 512 + threadIdx.x * 8) = *(const uint4*)o;
}

// Combined: reorder_wbf (blocks [0,512)) + beff2 (blocks [512,1024)) + blcat (rest)
__global__ void combo(const unsigned short* __restrict__ W, unsigned short* __restrict__ R,
                      const unsigned short* __restrict__ Wl, const float* __restrict__ blog,
                      const unsigned short* __restrict__ Wp2, const float* __restrict__ bp2,
                      const float* __restrict__ bc1, const float* __restrict__ bc2,
                      float* __restrict__ blcat, float* __restrict__ beff2) {
  const int lane = threadIdx.x & 63;
  if (blockIdx.x < 512) {
    const int id = blockIdx.x * 256 + threadIdx.x;  // 131072
    const int tid = id & 255, mi = (id >> 8) & 1, kk = (id >> 9) & 15, s = id >> 13;
    const int w = tid >> 6, ln = tid & 63, fr = ln & 15, kq = ln >> 4;
    const int row = s * 128 + w * 32 + mi * 16 + fr;
    const int col = kk * 32 + kq * 8;
    *((uint4*)R + id) = *(const uint4*)(W + (size_t)row * 512 + col);
  } else if (blockIdx.x < 1024) {
    const int m = (blockIdx.x - 512) * 4 + (threadIdx.x >> 6);
    const unsigned short* row = Wp2 + (size_t)m * 1024 + 512;
    float sum = 0.f;
    for (int k = lane; k < 512; k += 64) sum += bf2f(row[k]) * bc1[k];
#pragma unroll
    for (int mm = 32; mm; mm >>= 1) sum += __shfl_xor(sum, mm, 64);
    if (lane == 0) beff2[m] = bp2[m] + sum;
  } else {
    const int j = (blockIdx.x - 1024) * 4 + (threadIdx.x >> 6);  // < 10000
    const unsigned short* row = Wl + (size_t)j * 1536;
    float sum = 0.f;
    for (int k = lane; k < 512; k += 64) {
      sum += bf2f(row[512 + k]) * bc1[k];
      sum += bf2f(row[1024 + k]) * bc2[k];
    }
#pragma unroll
    for (int mm = 32; mm; mm >>= 1) sum += __shfl_xor(sum, mm, 64);
    if (lane == 0) blcat[j] = blog[j] + sum;
  }
}

// ================= host =================
extern "C" void kernel_launch(void* const* d_in, const int* in_sizes, int n_in,
                              void* d_out, int out_size, void* d_ws, size_t ws_size,
                              hipStream_t stream) {
  (void)in_sizes; (void)n_in; (void)out_size; (void)ws_size;
  const float* img    = (const float*)d_in[0];
  const int*   ix     = (const int*)d_in[1];
  const float* emb    = (const float*)d_in[2];
  const float* Wih1f  = (const float*)d_in[3];
  const float* bih1   = (const float*)d_in[4];
  const float* Wic1f  = (const float*)d_in[5];
  const float* bic1   = (const float*)d_in[6];
  const float* Wih2f  = (const float*)d_in[7];
  const float* bih2   = (const float*)d_in[8];
  const float* Wic2f  = (const float*)d_in[9];
  const float* bic2   = (const float*)d_in[10];
  const float* Wihl1  = (const float*)d_in[11];
  const float* Whhl1  = (const float*)d_in[12];
  const float* b1     = (const float*)d_in[13];
  const float* Wihl2  = (const float*)d_in[14];
  const float* Whhl2  = (const float*)d_in[15];
  const float* b2     = (const float*)d_in[16];
  const float* Wv1    = (const float*)d_in[17];
  const float* bv1    = (const float*)d_in[18];
  const float* Wo1    = (const float*)d_in[19];
  const float* bo1    = (const float*)d_in[20];
  const float* Wv2    = (const float*)d_in[21];
  const float* bv2    = (const float*)d_in[22];
  const float* Wo2    = (const float*)d_in[23];
  const float* bo2    = (const float*)d_in[24];
  const float* Wlog   = (const float*)d_in[25];
  const float* blog   = (const float*)d_in[26];
  float* out = (float*)d_out;

  char* p = (char*)d_ws;
  auto al = [&](size_t bytes) { char* r = p; p += (bytes + 255) & ~(size_t)255; return r; };
  unsigned short* Wp1    = (unsigned short*)al((size_t)2048 * 512 * 2);
  unsigned short* Whh1_b = (unsigned short*)al((size_t)2048 * 512 * 2);
  unsigned short* Wp2    = (unsigned short*)al((size_t)2048 * 1024 * 2);
  unsigned short* Whh2_b = (unsigned short*)al((size_t)2048 * 512 * 2);
  unsigned short* WvT1   = (unsigned short*)al((size_t)512 * 512 * 2);
  unsigned short* Wo1_b  = (unsigned short*)al((size_t)512 * 512 * 2);
  unsigned short* WvT2   = (unsigned short*)al((size_t)512 * 512 * 2);
  unsigned short* Wo2_b  = (unsigned short*)al((size_t)512 * 512 * 2);
  unsigned short* Wc1T   = (unsigned short*)al((size_t)512 * 512 * 2);
  unsigned short* Wc2T   = (unsigned short*)al((size_t)512 * 512 * 2);
  unsigned short* Wlog_b = (unsigned short*)al((size_t)10240 * 1536 * 2);
  unsigned short* Wcat   = (unsigned short*)al((size_t)10240 * 1024 * 2);
  unsigned short* Weff2  = (unsigned short*)al((size_t)2048 * 512 * 2);
  unsigned short* Weff2r = (unsigned short*)al((size_t)2048 * 512 * 2);
  unsigned short* Wh1i_b = (unsigned short*)al((size_t)512 * 2048 * 2);
  unsigned short* Wc1i_b = (unsigned short*)al((size_t)512 * 2048 * 2);
  unsigned short* Wh2i_b = (unsigned short*)al((size_t)512 * 2048 * 2);
  unsigned short* Wc2i_b = (unsigned short*)al((size_t)512 * 2048 * 2);
  unsigned short* img_b  = (unsigned short*)al((size_t)128 * 2048 * 2);
  unsigned short* x_b    = (unsigned short*)al((size_t)8192 * 512 * 2);
  float*          xpr    = (float*)al((size_t)8192 * 2048 * 4);
  unsigned short* hcat   = (unsigned short*)al((size_t)8192 * 1024 * 2);
  unsigned short* hx1    = (unsigned short*)al((size_t)64 * 128 * 512 * 2);
  unsigned short* hx2    = (unsigned short*)al((size_t)64 * 128 * 512 * 2);
  unsigned short* h01    = (unsigned short*)al((size_t)128 * 512 * 2);
  unsigned short* h02    = (unsigned short*)al((size_t)128 * 512 * 2);
  float*          c1st   = (float*)al((size_t)128 * 512 * 4);
  float*          c2st   = (float*)al((size_t)128 * 512 * 4);
  float*          bcat   = (float*)al((size_t)2048 * 4);
  float*          bp1    = (float*)al((size_t)2048 * 4);
  float*          bp2    = (float*)al((size_t)2048 * 4);
  float*          bc1    = (float*)al((size_t)512 * 4);
  float*          bc2    = (float*)al((size_t)512 * 4);
  float*          beff2  = (float*)al((size_t)2048 * 4);
  float*          blcat  = (float*)al((size_t)10240 * 4);
  int*            flags  = (int*)al(2048);

  hipMemsetAsync(flags, 0, 2048, stream);

  // ---- casts (vec4; emb handled by gather_rows) ----
  CastJobs J = {};
  auto addjob = [&](const float* s, unsigned short* d, long nreal, long ntot) {
    J.src[J.n] = s; J.dst[J.n] = d; J.nreal4[J.n] = nreal / 4;
    J.cum4[J.n + 1] = J.cum4[J.n] + ntot / 4; ++J.n;
  };
  addjob(img,   img_b,  (long)128 * 2048,   (long)128 * 2048);
  addjob(Whhl1, Whh1_b, (long)2048 * 512,   (long)2048 * 512);
  addjob(Whhl2, Whh2_b, (long)2048 * 512,   (long)2048 * 512);
  addjob(Wo1,   Wo1_b,  (long)512 * 512,    (long)512 * 512);
  addjob(Wo2,   Wo2_b,  (long)512 * 512,    (long)512 * 512);
  addjob(Wih1f, Wh1i_b, (long)512 * 2048,   (long)512 * 2048);
  addjob(Wic1f, Wc1i_b, (long)512 * 2048,   (long)512 * 2048);
  addjob(Wih2f, Wh2i_b, (long)512 * 2048,   (long)512 * 2048);
  addjob(Wic2f, Wc2i_b, (long)512 * 2048,   (long)512 * 2048);
  addjob(Wlog,  Wlog_b, (long)10000 * 1536, (long)10240 * 1536);
  cast_multi4<<<2048, 256, 0, stream>>>(J);

  prep1<<<1024, 256, 0, stream>>>(Wv1, Wv2, Wihl1, Wihl2, b1, b2,
                                  bih1, bic1, bih2, bic2,
                                  Wo1, bv1, bo1, Wo2, bv2, bo2,
                                  WvT1, WvT2, Wp1, Wp2, bp1, bp2, bcat, bc1, bc2);

  gather_rows<<<8192, 64, 0, stream>>>(ix, emb, x_b);

  // ---- batch A: xp1 (MODE2) | WcT1 | WcT2 (MODE1) | init (MODE3) ----
  {
    GJobs B = {};
    B.j[0] = {Wp1, x_b, xpr, nullptr, nullptr, nullptr, bp1,
              512, 512, 0, 0, 512, 8192, 16, 2, 1024, 0};
    B.j[1] = {WvT1, Wo1_b, Wc1T, nullptr, nullptr, nullptr, nullptr,
              512, 512, 512, 0, 512, 512, 4, 1, 1040, 0};
    B.j[2] = {WvT2, Wo2_b, Wc2T, nullptr, nullptr, nullptr, nullptr,
              512, 512, 512, 0, 512, 512, 4, 1, 1056, 0};
    B.j[3] = {img_b, Wh1i_b, h01, c1st, h02, c2st, bcat,
              2048, 2048, 0, 0, 2048, 2048, 1, 3, 1072, 0};
    gemm_batch<<<1072, 256, 0, stream>>>(B);
  }

  // ---- batch B: Wcat-a (MODE4) | Wcat-b (MODE1) | Weff2 fold (MODE4) ----
  {
    GJobs B = {};
    B.j[0] = {Wlog_b + 1024, Wc2T, Wcat, Wlog_b, nullptr, nullptr, nullptr,
              1536, 512, 1024, 1536, 512, 512, 80, 4, 320, 0};
    B.j[1] = {Wlog_b + 512, Wc1T, Wcat + 512, nullptr, nullptr, nullptr, nullptr,
              1536, 512, 1024, 0, 512, 512, 80, 1, 640, 0};
    B.j[2] = {Wp2 + 512, Wc1T, Weff2, Wp2, nullptr, nullptr, nullptr,
              1024, 512, 512, 1024, 512, 512, 16, 4, 704, 0};
    gemm_batch<<<704, 256, 0, stream>>>(B);
  }

  // ---- combo: reorder Weff2 + beff2 + blcat ----
  combo<<<3524, 256, 0, stream>>>(Weff2, Weff2r, Wlog_b, blog, Wp2, bp2,
                                  bc1, bc2, blcat, beff2);

  // ---- both LSTMs, fused & pipelined (R13-exact) ----
  lstm_fused<<<256, 256, 0, stream>>>(
      Whh1_b, Whh2_b, Weff2r, h01, h02, c1st, c2st, xpr, beff2, hx1, hx2, hcat, flags);

  // ---- logits = hcat @ Wcat^T + blcat (R14-exact epilogue) ----
  gemm256<<<dim3(32, 40), 512, 0, stream>>>(
      hcat, 1024, Wcat, 1024, out, 10000, blcat, 1024, 10000);
}

// Round 17
// 751.705 us; speedup vs baseline: 2.1282x; 1.0203x over previous
//
#include <hip/hip_runtime.h>
#include <stdint.h>

#define DEV __device__ __forceinline__

typedef short bf16x8 __attribute__((ext_vector_type(8)));
typedef float f32x4 __attribute__((ext_vector_type(4)));

DEV unsigned short f2bf(float f) {
  union { float f; uint32_t u; } v; v.f = f;
  return (unsigned short)((v.u + 0x7fffu + ((v.u >> 16) & 1u)) >> 16);
}
DEV float bf2f(unsigned short u) {
  union { uint32_t u; float f; } v; v.u = (uint32_t)u << 16; return v.f;
}

DEV float fsig(float x) { return 1.f / (1.f + __expf(-x)); }
DEV float ftanh(float x) { float e = __expf(2.f * x); return 1.f - 2.f / (e + 1.f); }

DEV void gload16(const void* g, void* lds) {
  __builtin_amdgcn_global_load_lds(
      (const __attribute__((address_space(1))) int*)(uintptr_t)g,
      (__attribute__((address_space(3))) int*)(uintptr_t)lds, 16, 0, 0);
}

// ================= batched NT GEMM: up to 4 jobs per launch =================
struct GJob {
  const unsigned short* A; const unsigned short* B;
  void *P0, *P1, *P2, *P3;
  const float* bias;
  int lda, ldb, ldc, ldc2, K, Nreal, gx, mode, wg_end, pad;
};
struct GJobs { GJob j[4]; };

__global__ __launch_bounds__(256) void gemm_batch(GJobs JB) {
  int ji = 0;
  while ((int)blockIdx.x >= JB.j[ji].wg_end) ++ji;
  const GJob J = JB.j[ji];
  const int wg = blockIdx.x - (ji ? JB.j[ji - 1].wg_end : 0);

  __shared__ alignas(16) unsigned short Asm[128 * 32];
  __shared__ alignas(16) unsigned short Bsm[128 * 32];
  const int tid = threadIdx.x;
  const int wave = tid >> 6, lane = tid & 63;
  const int m0 = (wg % J.gx) * 128, n0 = (wg / J.gx) * 128;
  const int wr = wave >> 1, wc = wave & 1;

  f32x4 acc[4][4] = {};

  const int q0 = tid, q1 = tid + 256;
  const unsigned short* Ag0 = J.A + (size_t)(m0 + (q0 >> 2)) * J.lda + (q0 & 3) * 8;
  const unsigned short* Ag1 = J.A + (size_t)(m0 + (q1 >> 2)) * J.lda + (q1 & 3) * 8;
  const unsigned short* Bg0 = J.B + (size_t)(n0 + (q0 >> 2)) * J.ldb + (q0 & 3) * 8;
  const unsigned short* Bg1 = J.B + (size_t)(n0 + (q1 >> 2)) * J.ldb + (q1 & 3) * 8;
  char* As0 = (char*)Asm + wave * 1024;  char* As1 = As0 + 4096;
  char* Bs0 = (char*)Bsm + wave * 1024;  char* Bs1 = Bs0 + 4096;

  const int ra = wr * 64 + (lane & 15);
  const int rb = wc * 64 + (lane & 15);
  const int kb = (lane >> 4) * 16;

  for (int k0 = 0; k0 < J.K; k0 += 32) {
    gload16(Ag0 + k0, As0);
    gload16(Ag1 + k0, As1);
    gload16(Bg0 + k0, Bs0);
    gload16(Bg1 + k0, Bs1);
    __syncthreads();
    bf16x8 af[4], bfr[4];
#pragma unroll
    for (int i = 0; i < 4; ++i)
      af[i] = *(const bf16x8*)((const char*)Asm + (ra + i * 16) * 64 + kb);
#pragma unroll
    for (int i = 0; i < 4; ++i)
      bfr[i] = *(const bf16x8*)((const char*)Bsm + (rb + i * 16) * 64 + kb);
#pragma unroll
    for (int mi = 0; mi < 4; ++mi)
#pragma unroll
      for (int ni = 0; ni < 4; ++ni)
        acc[mi][ni] = __builtin_amdgcn_mfma_f32_16x16x32_bf16(af[mi], bfr[ni], acc[mi][ni], 0, 0, 0);
    __syncthreads();
  }

  const int row0 = m0 + wr * 64 + (lane >> 4) * 4;
  const int col0 = n0 + wc * 64 + (lane & 15);

  if (J.mode == 2) {
#pragma unroll
    for (int mi = 0; mi < 4; ++mi) {
      const int rowb = row0 + mi * 16;       // multiple of 4
      const int dd = rowb >> 2;
      const float4 b4 = *(const float4*)&J.bias[rowb];
#pragma unroll
      for (int ni = 0; ni < 4; ++ni) {
        const int col = col0 + ni * 16;
        const int tt = col & 63, bb = col >> 6;
        float4 v;
        v.x = acc[mi][ni][0] + b4.x;
        v.y = acc[mi][ni][1] + b4.y;
        v.z = acc[mi][ni][2] + b4.z;
        v.w = acc[mi][ni][3] + b4.w;
        const int wgid = (bb >> 4) * 16 + (dd >> 5);
        const int ww = (dd >> 3) & 3, mi2 = (dd >> 2) & 1, ln = (dd & 3) * 16 + (bb & 15);
        ((float4*)J.P0)[((((size_t)tt * 128 + wgid) * 4 + ww) * 2 + mi2) * 64 + ln] = v;
      }
    }
    return;
  }

#pragma unroll
  for (int mi = 0; mi < 4; ++mi) {
#pragma unroll
    for (int ni = 0; ni < 4; ++ni) {
      const int col = col0 + ni * 16;
      if (col >= J.Nreal) continue;
      const float bs = J.bias ? J.bias[col] : 0.f;
#pragma unroll
      for (int rr = 0; rr < 4; ++rr) {
        const int row = row0 + mi * 16 + rr;
        const float v = acc[mi][ni][rr] + bs;
        if (J.mode == 1) {
          ((unsigned short*)J.P0)[(size_t)row * J.ldc + col] = f2bf(v);
          if (J.P1) ((unsigned short*)J.P1)[(size_t)row * J.ldc2 + col] = f2bf(v);
        } else if (J.mode == 4) {
          const unsigned short ad = ((const unsigned short*)J.P1)[(size_t)row * J.ldc2 + col];
          ((unsigned short*)J.P0)[(size_t)row * J.ldc + col] = f2bf(v + bf2f(ad));
        } else {  // mode 3
          const int seg = col >> 9, cc = col & 511;
          if (seg == 0)      ((unsigned short*)J.P0)[(size_t)row * 512 + cc] = f2bf(v);
          else if (seg == 1) ((float*)J.P1)[(size_t)row * 512 + cc] = v;
          else if (seg == 2) ((unsigned short*)J.P2)[(size_t)row * 512 + cc] = f2bf(v);
          else               ((float*)J.P3)[(size_t)row * 512 + cc] = v;
        }
      }
    }
  }
}

// ============ 256x256 tile GEMM, BK=64, counted vmcnt pipeline, NT C-stores ============
// R14-exact epilogue (per-lane 4B NT stores cover 4 full 64B lines per wave store).
__global__ __launch_bounds__(512, 2) void gemm256(
    const unsigned short* __restrict__ A, int lda,
    const unsigned short* __restrict__ B, int ldb,
    float* __restrict__ C, int ldc,
    const float* __restrict__ bias, int K, int Nreal)
{
  __shared__ alignas(16) unsigned short Lds[2][2][16384];
  const int tid = threadIdx.x;
  const int wave = tid >> 6, lane = tid & 63;
  const int fr = lane & 15, kq = lane >> 4;

  const int gx = gridDim.x;
  const int lin = blockIdx.y * gx + blockIdx.x;
  const int nwg = gx * gridDim.y;
  const int q8 = nwg >> 3, r8 = nwg & 7;
  const int xcd = lin & 7, i2 = lin >> 3;
  const int wg = (xcd < r8 ? xcd * (q8 + 1) : r8 * (q8 + 1) + (xcd - r8) * q8) + i2;
  const int m0 = (wg % gx) * 256, n0 = (wg / gx) * 256;

  const int wr = wave >> 2, wc = wave & 3;

  const unsigned short* srcA[4];
  const unsigned short* srcB[4];
  int dstO[4];
#pragma unroll
  for (int s = 0; s < 4; ++s) {
    const int c = tid + s * 512;
    const int row = c >> 3, qp = (c & 7) ^ (row & 7);
    srcA[s] = A + (size_t)(m0 + row) * lda + qp * 8;
    srcB[s] = B + (size_t)(n0 + row) * ldb + qp * 8;
    dstO[s] = (wave * 64 + s * 512) * 16;
  }

  const int NT = K >> 6;
#define STAGE256(kt, buf)                                            \
  {                                                                  \
    _Pragma("unroll")                                                \
    for (int s = 0; s < 4; ++s)                                      \
      gload16(srcA[s] + (kt) * 64, (char*)&Lds[buf][0][0] + dstO[s]);\
    _Pragma("unroll")                                                \
    for (int s = 0; s < 4; ++s)                                      \
      gload16(srcB[s] + (kt) * 64, (char*)&Lds[buf][1][0] + dstO[s]);\
  }
  STAGE256(0, 0);
  STAGE256(1, 1);

  f32x4 acc[8][4] = {};
  const int slot0 = (kq ^ (fr & 7)) * 16;

  for (int kt = 0; kt < NT; ++kt) {
    asm volatile("s_waitcnt vmcnt(8)" ::: "memory");
    __builtin_amdgcn_sched_barrier(0);
    __builtin_amdgcn_s_barrier();
    __builtin_amdgcn_sched_barrier(0);
    const char* bufA = (const char*)&Lds[kt & 1][0][0];
    const char* bufB = (const char*)&Lds[kt & 1][1][0];
    bf16x8 Bf[4][2];
#pragma unroll
    for (int n = 0; n < 4; ++n) {
      const char* bb = bufB + (wc * 64 + n * 16 + fr) * 128;
      Bf[n][0] = *(const bf16x8*)(bb + slot0);
      Bf[n][1] = *(const bf16x8*)(bb + (slot0 ^ 64));
    }
#pragma unroll
    for (int q = 0; q < 4; ++q) {
      bf16x8 Af[2][2];
#pragma unroll
      for (int m2 = 0; m2 < 2; ++m2) {
        const char* ab = bufA + (wr * 128 + q * 32 + m2 * 16 + fr) * 128;
        Af[m2][0] = *(const bf16x8*)(ab + slot0);
        Af[m2][1] = *(const bf16x8*)(ab + (slot0 ^ 64));
      }
      __builtin_amdgcn_s_setprio(1);
#pragma unroll
      for (int m2 = 0; m2 < 2; ++m2)
#pragma unroll
        for (int n = 0; n < 4; ++n) {
          acc[q * 2 + m2][n] = __builtin_amdgcn_mfma_f32_16x16x32_bf16(
              Af[m2][0], Bf[n][0], acc[q * 2 + m2][n], 0, 0, 0);
          acc[q * 2 + m2][n] = __builtin_amdgcn_mfma_f32_16x16x32_bf16(
              Af[m2][1], Bf[n][1], acc[q * 2 + m2][n], 0, 0, 0);
        }
      __builtin_amdgcn_s_setprio(0);
    }
    __builtin_amdgcn_sched_barrier(0);
    __builtin_amdgcn_s_barrier();
    __builtin_amdgcn_sched_barrier(0);
    const int kn = (kt + 2 < NT) ? kt + 2 : 0;
    STAGE256(kn, kt & 1);
  }

#pragma unroll
  for (int mf = 0; mf < 8; ++mf) {
    const int row = m0 + wr * 128 + mf * 16 + kq * 4;
#pragma unroll
    for (int n = 0; n < 4; ++n) {
      const int col = n0 + wc * 64 + n * 16 + fr;
      if (col < Nreal) {
        const float bs = bias[col];
#pragma unroll
        for (int rr = 0; rr < 4; ++rr)
          __builtin_nontemporal_store(acc[mf][n][rr] + bs,
                                      &C[(size_t)(row + rr) * ldc + col]);
      }
    }
  }
#undef STAGE256
}

// ================= fused persistent LSTM1+LSTM2 (256 WGs, 1/CU) =================
// R13-exact (AGENT-scope LLC exchange, split phase B, late fl2 poll).
__global__ __launch_bounds__(256, 1) void lstm_fused(
    const unsigned short* __restrict__ Whh1, const unsigned short* __restrict__ Whh2,
    const unsigned short* __restrict__ Weff2r,  // [16 s][16 kk][2 mi][256 tid][8] bf16
    const unsigned short* __restrict__ h01, const unsigned short* __restrict__ h02,
    const float* __restrict__ c1st, const float* __restrict__ c2st,
    const float* __restrict__ xpr,              // [64][128][4][2][64][4] f32
    const float* __restrict__ beff2,            // [2048] gate-interleaved
    unsigned short* __restrict__ hx1, unsigned short* __restrict__ hx2,
    unsigned short* __restrict__ hcat,          // [8192][1024]: [h2s | h1s]
    int* __restrict__ flags)                    // [2][8][16] ints
{
  __shared__ unsigned short Wsm[8][128][64];
  __shared__ uint32_t Hst[16][16];              // packed h staging (1KB)
  const int tid = threadIdx.x;
  const bool role2 = blockIdx.x >= 128;
  const int wg = role2 ? blockIdx.x - 128 : blockIdx.x;
  const int g = wg >> 4, s = wg & 15;
  const int w = tid >> 6, lane = tid & 63, fr = lane & 15, kq = lane >> 4;

  // ---- stage Whh slice into LDS (slot = chunk ^ (m&7)) ----
  {
    const unsigned short* Whh = role2 ? Whh2 : Whh1;
    const int m = tid >> 1;
    const int row = (m & 3) * 512 + s * 32 + (m >> 2);
    const unsigned short* src = Whh + (size_t)row * 512 + (tid & 1) * 256;
#pragma unroll 4
    for (int cc = 0; cc < 32; ++cc) {
      const int k = (tid & 1) * 256 + cc * 8;
      uint4 v = *(const uint4*)(src + cc * 8);
      const int kblk = k >> 6, c = (k & 63) >> 3, sl = c ^ (m & 7);
      *(uint4*)((char*)&Wsm[kblk][m][0] + sl * 16) = v;
    }
  }

  const int b = g * 16 + fr;
  const int d0 = s * 32 + w * 8 + kq;
  const float* c0 = role2 ? c2st : c1st;
  float c_r[2];
  c_r[0] = c0[b * 512 + d0];
  c_r[1] = c0[b * 512 + d0 + 4];
  __syncthreads();

  int* fl1 = flags + g * 16;
  int* fl2 = flags + 128 + g * 16;
  int* flown = role2 ? fl2 : fl1;
  unsigned short* hxown = role2 ? hx2 : hx1;
  const unsigned short* hinit = role2 ? h02 : h01;
  const int colbase = (role2 ? 0 : 512) + s * 32;
  const float4* xv = (const float4*)xpr + ((size_t)(wg * 4 + w) * 2) * 64 + lane;
  float4 be0 = {0, 0, 0, 0}, be1 = {0, 0, 0, 0};
  if (role2) {
    be0 = *(const float4*)(beff2 + s * 128 + w * 32 + kq * 4);
    be1 = *(const float4*)(beff2 + s * 128 + w * 32 + 16 + kq * 4);
  }
  const size_t hxg = (size_t)g * 8192;           // per-t region offset for group

  for (int t = 0; t < 64; ++t) {
    f32x4 acc[2] = {};
    float4 xg0, xg1;

    if (!role2) {
      xg0 = xv[(size_t)t * 65536];               // HBM prefetch before poll
      xg1 = xv[(size_t)t * 65536 + 64];
      // ---- poll: own group's h1(t-1) posted ----
      if (t) {
        if (w == 1) {
          for (;;) {
            bool ok = true;
            if (lane < 16)
              ok = __hip_atomic_load(fl1 + lane, __ATOMIC_RELAXED,
                                     __HIP_MEMORY_SCOPE_AGENT) >= t;
            if (__all(ok)) break;
            __builtin_amdgcn_s_sleep(1);
          }
        }
        __syncthreads();
      }
      // ---- own-h fragments ----
      bf16x8 hf[16];
      if (t == 0) {
#pragma unroll
        for (int kk = 0; kk < 16; ++kk)
          hf[kk] = *(const bf16x8*)(hinit + (size_t)b * 512 + kk * 32 + kq * 8);
      } else {
        const unsigned short* hb = hx1 + (size_t)(t - 1) * 65536 + hxg + fr * 32 + kq * 8;
#pragma unroll
        for (int kk = 0; kk < 16; ++kk)
          hf[kk] = *(const bf16x8*)(hb + kk * 512);
      }
      // ---- phase A: Whh1 @ h1 (LDS) ----
#pragma unroll
      for (int kk = 0; kk < 16; ++kk) {
        const int kblk = kk >> 1, cbase = (kk & 1) * 4 + kq;
#pragma unroll
        for (int mi = 0; mi < 2; ++mi) {
          const int m = w * 32 + mi * 16 + fr;
          const int sl = cbase ^ (m & 7);
          const bf16x8 af = *(const bf16x8*)((const char*)&Wsm[kblk][m][0] + sl * 16);
          acc[mi] = __builtin_amdgcn_mfma_f32_16x16x32_bf16(af, hf[kk], acc[mi], 0, 0, 0);
        }
      }
    } else {
      xg0 = be0; xg1 = be1;
      // ---- poll: h1(t) posted (role1 runs ahead -> usually instant) ----
      if (w == 1) {
        for (;;) {
          bool ok = true;
          if (lane < 16)
            ok = __hip_atomic_load(fl1 + lane, __ATOMIC_RELAXED,
                                   __HIP_MEMORY_SCOPE_AGENT) >= t + 1;
          if (__all(ok)) break;
          __builtin_amdgcn_s_sleep(1);
        }
      }
      __syncthreads();
      const unsigned short* h1b = hx1 + (size_t)t * 65536 + hxg + fr * 32 + kq * 8;
      bf16x8 hf1[16];
#pragma unroll
      for (int kk = 0; kk < 16; ++kk)
        hf1[kk] = *(const bf16x8*)(h1b + kk * 512);
      const bf16x8* wr = (const bf16x8*)Weff2r + (size_t)s * 32 * 256 + tid;
      // ---- phase B first half (kk 0..7) ----
#pragma unroll
      for (int kk = 0; kk < 8; ++kk) {
#pragma unroll
        for (int mi = 0; mi < 2; ++mi)
          acc[mi] = __builtin_amdgcn_mfma_f32_16x16x32_bf16(
              wr[(kk * 2 + mi) * 256], hf1[kk], acc[mi], 0, 0, 0);
      }
      // ---- late poll of own cohort; then ISSUE h2 loads ----
      if (t) {
        if (w == 1) {
          for (;;) {
            bool ok = true;
            if (lane < 16)
              ok = __hip_atomic_load(fl2 + lane, __ATOMIC_RELAXED,
                                     __HIP_MEMORY_SCOPE_AGENT) >= t;
            if (__all(ok)) break;
            __builtin_amdgcn_s_sleep(1);
          }
        }
        __syncthreads();
      }
      bf16x8 hf2[16];
      if (t == 0) {
#pragma unroll
        for (int kk = 0; kk < 16; ++kk)
          hf2[kk] = *(const bf16x8*)(hinit + (size_t)b * 512 + kk * 32 + kq * 8);
      } else {
        const unsigned short* hb = hx2 + (size_t)(t - 1) * 65536 + hxg + fr * 32 + kq * 8;
#pragma unroll
        for (int kk = 0; kk < 16; ++kk)
          hf2[kk] = *(const bf16x8*)(hb + kk * 512);
      }
      // ---- phase B second half (kk 8..15): covers the h2 LLC fetch ----
#pragma unroll
      for (int kk = 8; kk < 16; ++kk) {
#pragma unroll
        for (int mi = 0; mi < 2; ++mi)
          acc[mi] = __builtin_amdgcn_mfma_f32_16x16x32_bf16(
              wr[(kk * 2 + mi) * 256], hf1[kk], acc[mi], 0, 0, 0);
      }
      // ---- phase A: Whh2 @ h2 (LDS), accumulate ----
#pragma unroll
      for (int kk = 0; kk < 16; ++kk) {
        const int kblk = kk >> 1, cbase = (kk & 1) * 4 + kq;
#pragma unroll
        for (int mi = 0; mi < 2; ++mi) {
          const int m = w * 32 + mi * 16 + fr;
          const int sl = cbase ^ (m & 7);
          const bf16x8 af = *(const bf16x8*)((const char*)&Wsm[kblk][m][0] + sl * 16);
          acc[mi] = __builtin_amdgcn_mfma_f32_16x16x32_bf16(af, hf2[kk], acc[mi], 0, 0, 0);
        }
      }
    }

    // ---- gates (lane-local) ----
    unsigned short hn[2];
#pragma unroll
    for (int mi = 0; mi < 2; ++mi) {
      const float4 xg = mi ? xg1 : xg0;
      const float iv = acc[mi][0] + xg.x;
      const float fv = acc[mi][1] + xg.y;
      const float gv = acc[mi][2] + xg.z;
      const float ov = acc[mi][3] + xg.w;
      const float c = fsig(fv) * c_r[mi] + fsig(iv) * ftanh(gv);
      c_r[mi] = c;
      hn[mi] = f2bf(fsig(ov) * ftanh(c));
    }

    // ---- pack to d-linear order: shfl + perm, stage in LDS ----
    const uint32_t pk = (uint32_t)hn[0] | ((uint32_t)hn[1] << 16);   // (d, d+4)
    const uint32_t y = (uint32_t)__shfl_xor((int)pk, 16);            // partner kq^1
    const uint32_t word = (kq & 1) ? __builtin_amdgcn_perm(pk, y, 0x07060302)
                                   : __builtin_amdgcn_perm(y, pk, 0x05040100);
    Hst[fr][w * 4 + ((kq & 1) ? 2 + (kq >> 1) : (kq >> 1))] = word;
    __syncthreads();

    // ---- wave 0: wide exchange stores (AGENT) + flag + hcat ----
    if (w == 0) {
      const uint4 v = *(const uint4*)&Hst[lane >> 2][(lane & 3) * 4];
      unsigned short* dst = hxown + (size_t)t * 65536 + hxg + s * 512 + lane * 8;
      __hip_atomic_store((unsigned long long*)dst, ((const unsigned long long*)&v)[0],
                         __ATOMIC_RELAXED, __HIP_MEMORY_SCOPE_AGENT);
      __hip_atomic_store((unsigned long long*)(dst + 4), ((const unsigned long long*)&v)[1],
                         __ATOMIC_RELAXED, __HIP_MEMORY_SCOPE_AGENT);
      asm volatile("s_waitcnt vmcnt(0)" ::: "memory");
      if (lane == 0)
        __hip_atomic_store(flown + s, t + 1, __ATOMIC_RELAXED, __HIP_MEMORY_SCOPE_AGENT);
      const int row = (g * 16 + (lane >> 2)) * 64 + t;
      *(uint4*)(hcat + (size_t)row * 1024 + colbase + (lane & 3) * 8) = v;
    }
  }
}

// ================= fused prep head: casts + weight perms + gather + flag clear =======
struct CastJobs {
  const float* src[12];
  unsigned short* dst[12];
  long nreal4[12];
  long cum4[13];
  int n;
};

struct Prep0Args {
  CastJobs J;
  const float *Wv1, *Wv2, *Wihl1, *Wihl2, *b1, *b2;
  const float *bih1, *bic1, *bih2, *bic2;
  const float *Wo1, *bv1, *bo1, *Wo2, *bv2, *bo2;
  unsigned short *WvT1, *WvT2, *Wp1, *Wp2;
  float *bp1, *bp2, *bcat, *bc1, *bc2;
  const int* ix; const float* emb; unsigned short* x_b;
  int* flags;
};

// grid 5121 x 256: [0,2048) casts | [2048,3072) prep | [3072,5120) gather | 5120 flags
__global__ __launch_bounds__(256) void prep0(Prep0Args A) {
  const int bid = blockIdx.x, tid = threadIdx.x;
  if (bid < 2048) {
    const CastJobs& J = A.J;
    const long total = J.cum4[J.n];
    for (long i = (long)bid * 256 + tid; i < total; i += (long)2048 * 256) {
      int s = 0;
      while (i >= J.cum4[s + 1]) ++s;
      const long off = i - J.cum4[s];
      float4 v = {0.f, 0.f, 0.f, 0.f};
      if (off < J.nreal4[s]) v = ((const float4*)J.src[s])[off];
      ushort4 o;
      o.x = f2bf(v.x); o.y = f2bf(v.y); o.z = f2bf(v.z); o.w = f2bf(v.w);
      ((ushort4*)J.dst[s])[off] = o;
    }
  } else if (bid < 3072) {
    const long NTOT = 924672;
    for (long id = (long)(bid - 2048) * 256 + tid; id < NTOT; id += (long)1024 * 256) {
      if (id < 131072) {              // perm W_ih1 by-8
        const int m = (int)(id >> 6), kb = (int)(id & 63) * 8;
        const float* sp = A.Wihl1 + (size_t)((m & 3) * 512 + (m >> 2)) * 512 + kb;
        unsigned short o[8];
#pragma unroll
        for (int e = 0; e < 8; ++e) o[e] = f2bf(sp[e]);
        *(uint4*)(A.Wp1 + (size_t)m * 512 + kb) = *(const uint4*)o;
      } else if (id < 393216) {       // perm W_ih2 by-8
        const long j = id - 131072;
        const int m = (int)(j >> 7), kb = (int)(j & 127) * 8;
        const float* sp = A.Wihl2 + (size_t)((m & 3) * 512 + (m >> 2)) * 1024 + kb;
        unsigned short o[8];
#pragma unroll
        for (int e = 0; e < 8; ++e) o[e] = f2bf(sp[e]);
        *(uint4*)(A.Wp2 + (size_t)m * 1024 + kb) = *(const uint4*)o;
      } else if (id < 917504) {       // transposed cast of Wv1/Wv2
        const long t = id - 393216;
        const int which = (int)(t >> 18);
        const int u = (int)(t & 262143), a = u >> 9, bb = u & 511;
        (which ? A.WvT2 : A.WvT1)[u] = f2bf((which ? A.Wv2 : A.Wv1)[(size_t)bb * 512 + a]);
      } else if (id < 921600) {       // bias perms
        const int t = (int)(id - 917504);
        if (t < 2048) A.bp1[t] = A.b1[(t & 3) * 512 + (t >> 2)];
        else { const int m = t - 2048; A.bp2[m] = A.b2[(m & 3) * 512 + (m >> 2)]; }
      } else if (id < 923648) {       // bcat concat
        const int i = (int)(id - 921600);
        const float* sarr[4] = {A.bih1, A.bic1, A.bih2, A.bic2};
        A.bcat[i] = sarr[i >> 9][i & 511];
      } else {                        // bc = Wo @ bv + bo (1024 rows)
        const int i = (int)(id - 923648);
        const float* Wo = (i >= 512) ? A.Wo2 : A.Wo1;
        const float* bv = (i >= 512) ? A.bv2 : A.bv1;
        const float* bo = (i >= 512) ? A.bo2 : A.bo1;
        float* bc = (i >= 512) ? A.bc2 : A.bc1;
        const int r = i & 511;
        float sacc = bo[r];
        for (int k = 0; k < 512; k += 4) {
          const float4 wv = *(const float4*)(Wo + (size_t)r * 512 + k);
          const float4 bb = *(const float4*)(bv + k);
          sacc += wv.x * bb.x + wv.y * bb.y + wv.z * bb.z + wv.w * bb.w;
        }
        bc[r] = sacc;
      }
    }
  } else if (bid < 5120) {
    // gather + cast: 4 rows per block
    const int row = (bid - 3072) * 4 + (tid >> 6);
    const int lane = tid & 63;
    const int e = A.ix[row];
    const float4* s = (const float4*)(A.emb + (size_t)e * 512) + lane * 2;
    const float4 a = s[0], b = s[1];
    unsigned short o[8] = {f2bf(a.x), f2bf(a.y), f2bf(a.z), f2bf(a.w),
                           f2bf(b.x), f2bf(b.y), f2bf(b.z), f2bf(b.w)};
    *(uint4*)(A.x_b + (size_t)row * 512 + lane * 8) = *(const uint4*)o;
  } else {
    // zero flags (512 ints)
    A.flags[tid] = 0;
    A.flags[tid + 256] = 0;
  }
}

// Combined: reorder_wbf (blocks [0,512)) + beff2 (blocks [512,1024)) + blcat (rest)
__global__ void combo(const unsigned short* __restrict__ W, unsigned short* __restrict__ R,
                      const unsigned short* __restrict__ Wl, const float* __restrict__ blog,
                      const unsigned short* __restrict__ Wp2, const float* __restrict__ bp2,
                      const float* __restrict__ bc1, const float* __restrict__ bc2,
                      float* __restrict__ blcat, float* __restrict__ beff2) {
  const int lane = threadIdx.x & 63;
  if (blockIdx.x < 512) {
    const int id = blockIdx.x * 256 + threadIdx.x;  // 131072
    const int tid = id & 255, mi = (id >> 8) & 1, kk = (id >> 9) & 15, s = id >> 13;
    const int w = tid >> 6, ln = tid & 63, fr = ln & 15, kq = ln >> 4;
    const int row = s * 128 + w * 32 + mi * 16 + fr;
    const int col = kk * 32 + kq * 8;
    *((uint4*)R + id) = *(const uint4*)(W + (size_t)row * 512 + col);
  } else if (blockIdx.x < 1024) {
    const int m = (blockIdx.x - 512) * 4 + (threadIdx.x >> 6);
    const unsigned short* row = Wp2 + (size_t)m * 1024 + 512;
    float sum = 0.f;
    for (int k = lane; k < 512; k += 64) sum += bf2f(row[k]) * bc1[k];
#pragma unroll
    for (int mm = 32; mm; mm >>= 1) sum += __shfl_xor(sum, mm, 64);
    if (lane == 0) beff2[m] = bp2[m] + sum;
  } else {
    const int j = (blockIdx.x - 1024) * 4 + (threadIdx.x >> 6);  // < 10000
    const unsigned short* row = Wl + (size_t)j * 1536;
    float sum = 0.f;
    for (int k = lane; k < 512; k += 64) {
      sum += bf2f(row[512 + k]) * bc1[k];
      sum += bf2f(row[1024 + k]) * bc2[k];
    }
#pragma unroll
    for (int mm = 32; mm; mm >>= 1) sum += __shfl_xor(sum, mm, 64);
    if (lane == 0) blcat[j] = blog[j] + sum;
  }
}

// ================= host =================
extern "C" void kernel_launch(void* const* d_in, const int* in_sizes, int n_in,
                              void* d_out, int out_size, void* d_ws, size_t ws_size,
                              hipStream_t stream) {
  (void)in_sizes; (void)n_in; (void)out_size; (void)ws_size;
  const float* img    = (const float*)d_in[0];
  const int*   ix     = (const int*)d_in[1];
  const float* emb    = (const float*)d_in[2];
  const float* Wih1f  = (const float*)d_in[3];
  const float* bih1   = (const float*)d_in[4];
  const float* Wic1f  = (const float*)d_in[5];
  const float* bic1   = (const float*)d_in[6];
  const float* Wih2f  = (const float*)d_in[7];
  const float* bih2   = (const float*)d_in[8];
  const float* Wic2f  = (const float*)d_in[9];
  const float* bic2   = (const float*)d_in[10];
  const float* Wihl1  = (const float*)d_in[11];
  const float* Whhl1  = (const float*)d_in[12];
  const float* b1     = (const float*)d_in[13];
  const float* Wihl2  = (const float*)d_in[14];
  const float* Whhl2  = (const float*)d_in[15];
  const float* b2     = (const float*)d_in[16];
  const float* Wv1    = (const float*)d_in[17];
  const float* bv1    = (const float*)d_in[18];
  const float* Wo1    = (const float*)d_in[19];
  const float* bo1    = (const float*)d_in[20];
  const float* Wv2    = (const float*)d_in[21];
  const float* bv2    = (const float*)d_in[22];
  const float* Wo2    = (const float*)d_in[23];
  const float* bo2    = (const float*)d_in[24];
  const float* Wlog   = (const float*)d_in[25];
  const float* blog   = (const float*)d_in[26];
  float* out = (float*)d_out;

  char* p = (char*)d_ws;
  auto al = [&](size_t bytes) { char* r = p; p += (bytes + 255) & ~(size_t)255; return r; };
  unsigned short* Wp1    = (unsigned short*)al((size_t)2048 * 512 * 2);
  unsigned short* Whh1_b = (unsigned short*)al((size_t)2048 * 512 * 2);
  unsigned short* Wp2    = (unsigned short*)al((size_t)2048 * 1024 * 2);
  unsigned short* Whh2_b = (unsigned short*)al((size_t)2048 * 512 * 2);
  unsigned short* WvT1   = (unsigned short*)al((size_t)512 * 512 * 2);
  unsigned short* Wo1_b  = (unsigned short*)al((size_t)512 * 512 * 2);
  unsigned short* WvT2   = (unsigned short*)al((size_t)512 * 512 * 2);
  unsigned short* Wo2_b  = (unsigned short*)al((size_t)512 * 512 * 2);
  unsigned short* Wc1T   = (unsigned short*)al((size_t)512 * 512 * 2);
  unsigned short* Wc2T   = (unsigned short*)al((size_t)512 * 512 * 2);
  unsigned short* Wlog_b = (unsigned short*)al((size_t)10240 * 1536 * 2);
  unsigned short* Wcat   = (unsigned short*)al((size_t)10240 * 1024 * 2);
  unsigned short* Weff2  = (unsigned short*)al((size_t)2048 * 512 * 2);
  unsigned short* Weff2r = (unsigned short*)al((size_t)2048 * 512 * 2);
  unsigned short* Wh1i_b = (unsigned short*)al((size_t)512 * 2048 * 2);
  unsigned short* Wc1i_b = (unsigned short*)al((size_t)512 * 2048 * 2);
  unsigned short* Wh2i_b = (unsigned short*)al((size_t)512 * 2048 * 2);
  unsigned short* Wc2i_b = (unsigned short*)al((size_t)512 * 2048 * 2);
  unsigned short* img_b  = (unsigned short*)al((size_t)128 * 2048 * 2);
  unsigned short* x_b    = (unsigned short*)al((size_t)8192 * 512 * 2);
  float*          xpr    = (float*)al((size_t)8192 * 2048 * 4);
  unsigned short* hcat   = (unsigned short*)al((size_t)8192 * 1024 * 2);
  unsigned short* hx1    = (unsigned short*)al((size_t)64 * 128 * 512 * 2);
  unsigned short* hx2    = (unsigned short*)al((size_t)64 * 128 * 512 * 2);
  unsigned short* h01    = (unsigned short*)al((size_t)128 * 512 * 2);
  unsigned short* h02    = (unsigned short*)al((size_t)128 * 512 * 2);
  float*          c1st   = (float*)al((size_t)128 * 512 * 4);
  float*          c2st   = (float*)al((size_t)128 * 512 * 4);
  float*          bcat   = (float*)al((size_t)2048 * 4);
  float*          bp1    = (float*)al((size_t)2048 * 4);
  float*          bp2    = (float*)al((size_t)2048 * 4);
  float*          bc1    = (float*)al((size_t)512 * 4);
  float*          bc2    = (float*)al((size_t)512 * 4);
  float*          beff2  = (float*)al((size_t)2048 * 4);
  float*          blcat  = (float*)al((size_t)10240 * 4);
  int*            flags  = (int*)al(2048);

  // ---- fused prep head: casts + perms + gather + flag clear ----
  Prep0Args PA = {};
  auto addjob = [&](const float* s, unsigned short* d, long nreal, long ntot) {
    PA.J.src[PA.J.n] = s; PA.J.dst[PA.J.n] = d; PA.J.nreal4[PA.J.n] = nreal / 4;
    PA.J.cum4[PA.J.n + 1] = PA.J.cum4[PA.J.n] + ntot / 4; ++PA.J.n;
  };
  addjob(img,   img_b,  (long)128 * 2048,   (long)128 * 2048);
  addjob(Whhl1, Whh1_b, (long)2048 * 512,   (long)2048 * 512);
  addjob(Whhl2, Whh2_b, (long)2048 * 512,   (long)2048 * 512);
  addjob(Wo1,   Wo1_b,  (long)512 * 512,    (long)512 * 512);
  addjob(Wo2,   Wo2_b,  (long)512 * 512,    (long)512 * 512);
  addjob(Wih1f, Wh1i_b, (long)512 * 2048,   (long)512 * 2048);
  addjob(Wic1f, Wc1i_b, (long)512 * 2048,   (long)512 * 2048);
  addjob(Wih2f, Wh2i_b, (long)512 * 2048,   (long)512 * 2048);
  addjob(Wic2f, Wc2i_b, (long)512 * 2048,   (long)512 * 2048);
  addjob(Wlog,  Wlog_b, (long)10000 * 1536, (long)10240 * 1536);
  PA.Wv1 = Wv1; PA.Wv2 = Wv2; PA.Wihl1 = Wihl1; PA.Wihl2 = Wihl2;
  PA.b1 = b1; PA.b2 = b2;
  PA.bih1 = bih1; PA.bic1 = bic1; PA.bih2 = bih2; PA.bic2 = bic2;
  PA.Wo1 = Wo1; PA.bv1 = bv1; PA.bo1 = bo1; PA.Wo2 = Wo2; PA.bv2 = bv2; PA.bo2 = bo2;
  PA.WvT1 = WvT1; PA.WvT2 = WvT2; PA.Wp1 = Wp1; PA.Wp2 = Wp2;
  PA.bp1 = bp1; PA.bp2 = bp2; PA.bcat = bcat; PA.bc1 = bc1; PA.bc2 = bc2;
  PA.ix = ix; PA.emb = emb; PA.x_b = x_b; PA.flags = flags;
  prep0<<<5121, 256, 0, stream>>>(PA);

  // ---- batch A: xp1 (MODE2) | WcT1 | WcT2 (MODE1) | init (MODE3) ----
  {
    GJobs B = {};
    B.j[0] = {Wp1, x_b, xpr, nullptr, nullptr, nullptr, bp1,
              512, 512, 0, 0, 512, 8192, 16, 2, 1024, 0};
    B.j[1] = {WvT1, Wo1_b, Wc1T, nullptr, nullptr, nullptr, nullptr,
              512, 512, 512, 0, 512, 512, 4, 1, 1040, 0};
    B.j[2] = {WvT2, Wo2_b, Wc2T, nullptr, nullptr, nullptr, nullptr,
              512, 512, 512, 0, 512, 512, 4, 1, 1056, 0};
    B.j[3] = {img_b, Wh1i_b, h01, c1st, h02, c2st, bcat,
              2048, 2048, 0, 0, 2048, 2048, 1, 3, 1072, 0};
    gemm_batch<<<1072, 256, 0, stream>>>(B);
  }

  // ---- batch B: Wcat-a (MODE4) | Wcat-b (MODE1) | Weff2 fold (MODE4) ----
  {
    GJobs B = {};
    B.j[0] = {Wlog_b + 1024, Wc2T, Wcat, Wlog_b, nullptr, nullptr, nullptr,
              1536, 512, 1024, 1536, 512, 512, 80, 4, 320, 0};
    B.j[1] = {Wlog_b + 512, Wc1T, Wcat + 512, nullptr, nullptr, nullptr, nullptr,
              1536, 512, 1024, 0, 512, 512, 80, 1, 640, 0};
    B.j[2] = {Wp2 + 512, Wc1T, Weff2, Wp2, nullptr, nullptr, nullptr,
              1024, 512, 512, 1024, 512, 512, 16, 4, 704, 0};
    gemm_batch<<<704, 256, 0, stream>>>(B);
  }

  // ---- combo: reorder Weff2 + beff2 + blcat ----
  combo<<<3524, 256, 0, stream>>>(Weff2, Weff2r, Wlog_b, blog, Wp2, bp2,
                                  bc1, bc2, blcat, beff2);

  // ---- both LSTMs, fused & pipelined (R13-exact) ----
  lstm_fused<<<256, 256, 0, stream>>>(
      Whh1_b, Whh2_b, Weff2r, h01, h02, c1st, c2st, xpr, beff2, hx1, hx2, hcat, flags);

  // ---- logits = hcat @ Wcat^T + blcat (R14-exact epilogue) ----
  gemm256<<<dim3(32, 40), 512, 0, stream>>>(
      hcat, 1024, Wcat, 1024, out, 10000, blcat, 1024, 10000);
}

// Round 18
// 737.387 us; speedup vs baseline: 2.1695x; 1.0194x over previous
//
#include <hip/hip_runtime.h>
#include <stdint.h>

#define DEV __device__ __forceinline__

typedef short bf16x8 __attribute__((ext_vector_type(8)));
typedef float f32x4 __attribute__((ext_vector_type(4)));

DEV unsigned short f2bf(float f) {
  union { float f; uint32_t u; } v; v.f = f;
  return (unsigned short)((v.u + 0x7fffu + ((v.u >> 16) & 1u)) >> 16);
}
DEV float bf2f(unsigned short u) {
  union { uint32_t u; float f; } v; v.u = (uint32_t)u << 16; return v.f;
}

DEV float fsig(float x) { return 1.f / (1.f + __expf(-x)); }
DEV float ftanh(float x) { float e = __expf(2.f * x); return 1.f - 2.f / (e + 1.f); }

DEV void gload16(const void* g, void* lds) {
  __builtin_amdgcn_global_load_lds(
      (const __attribute__((address_space(1))) int*)(uintptr_t)g,
      (__attribute__((address_space(3))) int*)(uintptr_t)lds, 16, 0, 0);
}

// ================= batched NT GEMM: up to 4 jobs per launch =================
struct GJob {
  const unsigned short* A; const unsigned short* B;
  void *P0, *P1, *P2, *P3;
  const float* bias;
  int lda, ldb, ldc, ldc2, K, Nreal, gx, mode, wg_end, pad;
};
struct GJobs { GJob j[4]; };

__global__ __launch_bounds__(256) void gemm_batch(GJobs JB) {
  int ji = 0;
  while ((int)blockIdx.x >= JB.j[ji].wg_end) ++ji;
  const GJob J = JB.j[ji];
  const int wg = blockIdx.x - (ji ? JB.j[ji - 1].wg_end : 0);

  __shared__ alignas(16) unsigned short Asm[128 * 32];
  __shared__ alignas(16) unsigned short Bsm[128 * 32];
  const int tid = threadIdx.x;
  const int wave = tid >> 6, lane = tid & 63;
  const int m0 = (wg % J.gx) * 128, n0 = (wg / J.gx) * 128;
  const int wr = wave >> 1, wc = wave & 1;

  f32x4 acc[4][4] = {};

  const int q0 = tid, q1 = tid + 256;
  const unsigned short* Ag0 = J.A + (size_t)(m0 + (q0 >> 2)) * J.lda + (q0 & 3) * 8;
  const unsigned short* Ag1 = J.A + (size_t)(m0 + (q1 >> 2)) * J.lda + (q1 & 3) * 8;
  const unsigned short* Bg0 = J.B + (size_t)(n0 + (q0 >> 2)) * J.ldb + (q0 & 3) * 8;
  const unsigned short* Bg1 = J.B + (size_t)(n0 + (q1 >> 2)) * J.ldb + (q1 & 3) * 8;
  char* As0 = (char*)Asm + wave * 1024;  char* As1 = As0 + 4096;
  char* Bs0 = (char*)Bsm + wave * 1024;  char* Bs1 = Bs0 + 4096;

  const int ra = wr * 64 + (lane & 15);
  const int rb = wc * 64 + (lane & 15);
  const int kb = (lane >> 4) * 16;

  for (int k0 = 0; k0 < J.K; k0 += 32) {
    gload16(Ag0 + k0, As0);
    gload16(Ag1 + k0, As1);
    gload16(Bg0 + k0, Bs0);
    gload16(Bg1 + k0, Bs1);
    __syncthreads();
    bf16x8 af[4], bfr[4];
#pragma unroll
    for (int i = 0; i < 4; ++i)
      af[i] = *(const bf16x8*)((const char*)Asm + (ra + i * 16) * 64 + kb);
#pragma unroll
    for (int i = 0; i < 4; ++i)
      bfr[i] = *(const bf16x8*)((const char*)Bsm + (rb + i * 16) * 64 + kb);
#pragma unroll
    for (int mi = 0; mi < 4; ++mi)
#pragma unroll
      for (int ni = 0; ni < 4; ++ni)
        acc[mi][ni] = __builtin_amdgcn_mfma_f32_16x16x32_bf16(af[mi], bfr[ni], acc[mi][ni], 0, 0, 0);
    __syncthreads();
  }

  const int row0 = m0 + wr * 64 + (lane >> 4) * 4;
  const int col0 = n0 + wc * 64 + (lane & 15);

  if (J.mode == 2) {
#pragma unroll
    for (int mi = 0; mi < 4; ++mi) {
      const int rowb = row0 + mi * 16;       // multiple of 4
      const int dd = rowb >> 2;
      const float4 b4 = *(const float4*)&J.bias[rowb];
#pragma unroll
      for (int ni = 0; ni < 4; ++ni) {
        const int col = col0 + ni * 16;
        const int tt = col & 63, bb = col >> 6;
        float4 v;
        v.x = acc[mi][ni][0] + b4.x;
        v.y = acc[mi][ni][1] + b4.y;
        v.z = acc[mi][ni][2] + b4.z;
        v.w = acc[mi][ni][3] + b4.w;
        const int wgid = (bb >> 4) * 16 + (dd >> 5);
        const int ww = (dd >> 3) & 3, mi2 = (dd >> 2) & 1, ln = (dd & 3) * 16 + (bb & 15);
        ((float4*)J.P0)[((((size_t)tt * 128 + wgid) * 4 + ww) * 2 + mi2) * 64 + ln] = v;
      }
    }
    return;
  }

#pragma unroll
  for (int mi = 0; mi < 4; ++mi) {
#pragma unroll
    for (int ni = 0; ni < 4; ++ni) {
      const int col = col0 + ni * 16;
      if (col >= J.Nreal) continue;
      const float bs = J.bias ? J.bias[col] : 0.f;
#pragma unroll
      for (int rr = 0; rr < 4; ++rr) {
        const int row = row0 + mi * 16 + rr;
        const float v = acc[mi][ni][rr] + bs;
        if (J.mode == 1) {
          ((unsigned short*)J.P0)[(size_t)row * J.ldc + col] = f2bf(v);
          if (J.P1) ((unsigned short*)J.P1)[(size_t)row * J.ldc2 + col] = f2bf(v);
        } else if (J.mode == 4) {
          const unsigned short ad = ((const unsigned short*)J.P1)[(size_t)row * J.ldc2 + col];
          ((unsigned short*)J.P0)[(size_t)row * J.ldc + col] = f2bf(v + bf2f(ad));
        } else {  // mode 3
          const int seg = col >> 9, cc = col & 511;
          if (seg == 0)      ((unsigned short*)J.P0)[(size_t)row * 512 + cc] = f2bf(v);
          else if (seg == 1) ((float*)J.P1)[(size_t)row * 512 + cc] = v;
          else if (seg == 2) ((unsigned short*)J.P2)[(size_t)row * 512 + cc] = f2bf(v);
          else               ((float*)J.P3)[(size_t)row * 512 + cc] = v;
        }
      }
    }
  }
}

// ============ 256x256 tile GEMM, BK=64, counted vmcnt pipeline, NT C-stores ============
// R14 epilogue. NEW: n-major tile order (consecutive wg -> consecutive n-tile, fixed m)
// so each XCD's contiguous chunk covers 4 m x 40 n: A footprint 2MB -> L2-resident,
// reused 40x; B becomes LLC-resident after first m-row.
__global__ __launch_bounds__(512, 2) void gemm256(
    const unsigned short* __restrict__ A, int lda,
    const unsigned short* __restrict__ B, int ldb,
    float* __restrict__ C, int ldc,
    const float* __restrict__ bias, int K, int Nreal)
{
  __shared__ alignas(16) unsigned short Lds[2][2][16384];
  const int tid = threadIdx.x;
  const int wave = tid >> 6, lane = tid & 63;
  const int fr = lane & 15, kq = lane >> 4;

  const int gx = gridDim.x;                       // = n-tiles (40)
  const int lin = blockIdx.y * gx + blockIdx.x;
  const int nwg = gx * gridDim.y;
  const int q8 = nwg >> 3, r8 = nwg & 7;
  const int xcd = lin & 7, i2 = lin >> 3;
  const int wg = (xcd < r8 ? xcd * (q8 + 1) : r8 * (q8 + 1) + (xcd - r8) * q8) + i2;
  const int n0 = (wg % gx) * 256, m0 = (wg / gx) * 256;   // n-major

  const int wr = wave >> 2, wc = wave & 3;

  const unsigned short* srcA[4];
  const unsigned short* srcB[4];
  int dstO[4];
#pragma unroll
  for (int s = 0; s < 4; ++s) {
    const int c = tid + s * 512;
    const int row = c >> 3, qp = (c & 7) ^ (row & 7);
    srcA[s] = A + (size_t)(m0 + row) * lda + qp * 8;
    srcB[s] = B + (size_t)(n0 + row) * ldb + qp * 8;
    dstO[s] = (wave * 64 + s * 512) * 16;
  }

  const int NT = K >> 6;
#define STAGE256(kt, buf)                                            \
  {                                                                  \
    _Pragma("unroll")                                                \
    for (int s = 0; s < 4; ++s)                                      \
      gload16(srcA[s] + (kt) * 64, (char*)&Lds[buf][0][0] + dstO[s]);\
    _Pragma("unroll")                                                \
    for (int s = 0; s < 4; ++s)                                      \
      gload16(srcB[s] + (kt) * 64, (char*)&Lds[buf][1][0] + dstO[s]);\
  }
  STAGE256(0, 0);
  STAGE256(1, 1);

  f32x4 acc[8][4] = {};
  const int slot0 = (kq ^ (fr & 7)) * 16;

  for (int kt = 0; kt < NT; ++kt) {
    asm volatile("s_waitcnt vmcnt(8)" ::: "memory");
    __builtin_amdgcn_sched_barrier(0);
    __builtin_amdgcn_s_barrier();
    __builtin_amdgcn_sched_barrier(0);
    const char* bufA = (const char*)&Lds[kt & 1][0][0];
    const char* bufB = (const char*)&Lds[kt & 1][1][0];
    bf16x8 Bf[4][2];
#pragma unroll
    for (int n = 0; n < 4; ++n) {
      const char* bb = bufB + (wc * 64 + n * 16 + fr) * 128;
      Bf[n][0] = *(const bf16x8*)(bb + slot0);
      Bf[n][1] = *(const bf16x8*)(bb + (slot0 ^ 64));
    }
#pragma unroll
    for (int q = 0; q < 4; ++q) {
      bf16x8 Af[2][2];
#pragma unroll
      for (int m2 = 0; m2 < 2; ++m2) {
        const char* ab = bufA + (wr * 128 + q * 32 + m2 * 16 + fr) * 128;
        Af[m2][0] = *(const bf16x8*)(ab + slot0);
        Af[m2][1] = *(const bf16x8*)(ab + (slot0 ^ 64));
      }
      __builtin_amdgcn_s_setprio(1);
#pragma unroll
      for (int m2 = 0; m2 < 2; ++m2)
#pragma unroll
        for (int n = 0; n < 4; ++n) {
          acc[q * 2 + m2][n] = __builtin_amdgcn_mfma_f32_16x16x32_bf16(
              Af[m2][0], Bf[n][0], acc[q * 2 + m2][n], 0, 0, 0);
          acc[q * 2 + m2][n] = __builtin_amdgcn_mfma_f32_16x16x32_bf16(
              Af[m2][1], Bf[n][1], acc[q * 2 + m2][n], 0, 0, 0);
        }
      __builtin_amdgcn_s_setprio(0);
    }
    __builtin_amdgcn_sched_barrier(0);
    __builtin_amdgcn_s_barrier();
    __builtin_amdgcn_sched_barrier(0);
    const int kn = (kt + 2 < NT) ? kt + 2 : 0;
    STAGE256(kn, kt & 1);
  }

#pragma unroll
  for (int mf = 0; mf < 8; ++mf) {
    const int row = m0 + wr * 128 + mf * 16 + kq * 4;
#pragma unroll
    for (int n = 0; n < 4; ++n) {
      const int col = n0 + wc * 64 + n * 16 + fr;
      if (col < Nreal) {
        const float bs = bias[col];
#pragma unroll
        for (int rr = 0; rr < 4; ++rr)
          __builtin_nontemporal_store(acc[mf][n][rr] + bs,
                                      &C[(size_t)(row + rr) * ldc + col]);
      }
    }
  }
#undef STAGE256
}

// ================= fused persistent LSTM1+LSTM2 (256 WGs, 1/CU) =================
// R13-exact (AGENT-scope LLC exchange, split phase B, late fl2 poll).
__global__ __launch_bounds__(256, 1) void lstm_fused(
    const unsigned short* __restrict__ Whh1, const unsigned short* __restrict__ Whh2,
    const unsigned short* __restrict__ Weff2r,  // [16 s][16 kk][2 mi][256 tid][8] bf16
    const unsigned short* __restrict__ h01, const unsigned short* __restrict__ h02,
    const float* __restrict__ c1st, const float* __restrict__ c2st,
    const float* __restrict__ xpr,              // [64][128][4][2][64][4] f32
    const float* __restrict__ beff2,            // [2048] gate-interleaved
    unsigned short* __restrict__ hx1, unsigned short* __restrict__ hx2,
    unsigned short* __restrict__ hcat,          // [8192][1024]: [h2s | h1s]
    int* __restrict__ flags)                    // [2][8][16] ints
{
  __shared__ unsigned short Wsm[8][128][64];
  __shared__ uint32_t Hst[16][16];              // packed h staging (1KB)
  const int tid = threadIdx.x;
  const bool role2 = blockIdx.x >= 128;
  const int wg = role2 ? blockIdx.x - 128 : blockIdx.x;
  const int g = wg >> 4, s = wg & 15;
  const int w = tid >> 6, lane = tid & 63, fr = lane & 15, kq = lane >> 4;

  // ---- stage Whh slice into LDS (slot = chunk ^ (m&7)) ----
  {
    const unsigned short* Whh = role2 ? Whh2 : Whh1;
    const int m = tid >> 1;
    const int row = (m & 3) * 512 + s * 32 + (m >> 2);
    const unsigned short* src = Whh + (size_t)row * 512 + (tid & 1) * 256;
#pragma unroll 4
    for (int cc = 0; cc < 32; ++cc) {
      const int k = (tid & 1) * 256 + cc * 8;
      uint4 v = *(const uint4*)(src + cc * 8);
      const int kblk = k >> 6, c = (k & 63) >> 3, sl = c ^ (m & 7);
      *(uint4*)((char*)&Wsm[kblk][m][0] + sl * 16) = v;
    }
  }

  const int b = g * 16 + fr;
  const int d0 = s * 32 + w * 8 + kq;
  const float* c0 = role2 ? c2st : c1st;
  float c_r[2];
  c_r[0] = c0[b * 512 + d0];
  c_r[1] = c0[b * 512 + d0 + 4];
  __syncthreads();

  int* fl1 = flags + g * 16;
  int* fl2 = flags + 128 + g * 16;
  int* flown = role2 ? fl2 : fl1;
  unsigned short* hxown = role2 ? hx2 : hx1;
  const unsigned short* hinit = role2 ? h02 : h01;
  const int colbase = (role2 ? 0 : 512) + s * 32;
  const float4* xv = (const float4*)xpr + ((size_t)(wg * 4 + w) * 2) * 64 + lane;
  float4 be0 = {0, 0, 0, 0}, be1 = {0, 0, 0, 0};
  if (role2) {
    be0 = *(const float4*)(beff2 + s * 128 + w * 32 + kq * 4);
    be1 = *(const float4*)(beff2 + s * 128 + w * 32 + 16 + kq * 4);
  }
  const size_t hxg = (size_t)g * 8192;           // per-t region offset for group

  for (int t = 0; t < 64; ++t) {
    f32x4 acc[2] = {};
    float4 xg0, xg1;

    if (!role2) {
      xg0 = xv[(size_t)t * 65536];               // HBM prefetch before poll
      xg1 = xv[(size_t)t * 65536 + 64];
      // ---- poll: own group's h1(t-1) posted ----
      if (t) {
        if (w == 1) {
          for (;;) {
            bool ok = true;
            if (lane < 16)
              ok = __hip_atomic_load(fl1 + lane, __ATOMIC_RELAXED,
                                     __HIP_MEMORY_SCOPE_AGENT) >= t;
            if (__all(ok)) break;
            __builtin_amdgcn_s_sleep(1);
          }
        }
        __syncthreads();
      }
      // ---- own-h fragments ----
      bf16x8 hf[16];
      if (t == 0) {
#pragma unroll
        for (int kk = 0; kk < 16; ++kk)
          hf[kk] = *(const bf16x8*)(hinit + (size_t)b * 512 + kk * 32 + kq * 8);
      } else {
        const unsigned short* hb = hx1 + (size_t)(t - 1) * 65536 + hxg + fr * 32 + kq * 8;
#pragma unroll
        for (int kk = 0; kk < 16; ++kk)
          hf[kk] = *(const bf16x8*)(hb + kk * 512);
      }
      // ---- phase A: Whh1 @ h1 (LDS) ----
#pragma unroll
      for (int kk = 0; kk < 16; ++kk) {
        const int kblk = kk >> 1, cbase = (kk & 1) * 4 + kq;
#pragma unroll
        for (int mi = 0; mi < 2; ++mi) {
          const int m = w * 32 + mi * 16 + fr;
          const int sl = cbase ^ (m & 7);
          const bf16x8 af = *(const bf16x8*)((const char*)&Wsm[kblk][m][0] + sl * 16);
          acc[mi] = __builtin_amdgcn_mfma_f32_16x16x32_bf16(af, hf[kk], acc[mi], 0, 0, 0);
        }
      }
    } else {
      xg0 = be0; xg1 = be1;
      // ---- poll: h1(t) posted (role1 runs ahead -> usually instant) ----
      if (w == 1) {
        for (;;) {
          bool ok = true;
          if (lane < 16)
            ok = __hip_atomic_load(fl1 + lane, __ATOMIC_RELAXED,
                                   __HIP_MEMORY_SCOPE_AGENT) >= t + 1;
          if (__all(ok)) break;
          __builtin_amdgcn_s_sleep(1);
        }
      }
      __syncthreads();
      const unsigned short* h1b = hx1 + (size_t)t * 65536 + hxg + fr * 32 + kq * 8;
      bf16x8 hf1[16];
#pragma unroll
      for (int kk = 0; kk < 16; ++kk)
        hf1[kk] = *(const bf16x8*)(h1b + kk * 512);
      const bf16x8* wr = (const bf16x8*)Weff2r + (size_t)s * 32 * 256 + tid;
      // ---- phase B first half (kk 0..7) ----
#pragma unroll
      for (int kk = 0; kk < 8; ++kk) {
#pragma unroll
        for (int mi = 0; mi < 2; ++mi)
          acc[mi] = __builtin_amdgcn_mfma_f32_16x16x32_bf16(
              wr[(kk * 2 + mi) * 256], hf1[kk], acc[mi], 0, 0, 0);
      }
      // ---- late poll of own cohort; then ISSUE h2 loads ----
      if (t) {
        if (w == 1) {
          for (;;) {
            bool ok = true;
            if (lane < 16)
              ok = __hip_atomic_load(fl2 + lane, __ATOMIC_RELAXED,
                                     __HIP_MEMORY_SCOPE_AGENT) >= t;
            if (__all(ok)) break;
            __builtin_amdgcn_s_sleep(1);
          }
        }
        __syncthreads();
      }
      bf16x8 hf2[16];
      if (t == 0) {
#pragma unroll
        for (int kk = 0; kk < 16; ++kk)
          hf2[kk] = *(const bf16x8*)(hinit + (size_t)b * 512 + kk * 32 + kq * 8);
      } else {
        const unsigned short* hb = hx2 + (size_t)(t - 1) * 65536 + hxg + fr * 32 + kq * 8;
#pragma unroll
        for (int kk = 0; kk < 16; ++kk)
          hf2[kk] = *(const bf16x8*)(hb + kk * 512);
      }
      // ---- phase B second half (kk 8..15): covers the h2 LLC fetch ----
#pragma unroll
      for (int kk = 8; kk < 16; ++kk) {
#pragma unroll
        for (int mi = 0; mi < 2; ++mi)
          acc[mi] = __builtin_amdgcn_mfma_f32_16x16x32_bf16(
              wr[(kk * 2 + mi) * 256], hf1[kk], acc[mi], 0, 0, 0);
      }
      // ---- phase A: Whh2 @ h2 (LDS), accumulate ----
#pragma unroll
      for (int kk = 0; kk < 16; ++kk) {
        const int kblk = kk >> 1, cbase = (kk & 1) * 4 + kq;
#pragma unroll
        for (int mi = 0; mi < 2; ++mi) {
          const int m = w * 32 + mi * 16 + fr;
          const int sl = cbase ^ (m & 7);
          const bf16x8 af = *(const bf16x8*)((const char*)&Wsm[kblk][m][0] + sl * 16);
          acc[mi] = __builtin_amdgcn_mfma_f32_16x16x32_bf16(af, hf2[kk], acc[mi], 0, 0, 0);
        }
      }
    }

    // ---- gates (lane-local) ----
    unsigned short hn[2];
#pragma unroll
    for (int mi = 0; mi < 2; ++mi) {
      const float4 xg = mi ? xg1 : xg0;
      const float iv = acc[mi][0] + xg.x;
      const float fv = acc[mi][1] + xg.y;
      const float gv = acc[mi][2] + xg.z;
      const float ov = acc[mi][3] + xg.w;
      const float c = fsig(fv) * c_r[mi] + fsig(iv) * ftanh(gv);
      c_r[mi] = c;
      hn[mi] = f2bf(fsig(ov) * ftanh(c));
    }

    // ---- pack to d-linear order: shfl + perm, stage in LDS ----
    const uint32_t pk = (uint32_t)hn[0] | ((uint32_t)hn[1] << 16);   // (d, d+4)
    const uint32_t y = (uint32_t)__shfl_xor((int)pk, 16);            // partner kq^1
    const uint32_t word = (kq & 1) ? __builtin_amdgcn_perm(pk, y, 0x07060302)
                                   : __builtin_amdgcn_perm(y, pk, 0x05040100);
    Hst[fr][w * 4 + ((kq & 1) ? 2 + (kq >> 1) : (kq >> 1))] = word;
    __syncthreads();

    // ---- wave 0: wide exchange stores (AGENT) + flag + hcat ----
    if (w == 0) {
      const uint4 v = *(const uint4*)&Hst[lane >> 2][(lane & 3) * 4];
      unsigned short* dst = hxown + (size_t)t * 65536 + hxg + s * 512 + lane * 8;
      __hip_atomic_store((unsigned long long*)dst, ((const unsigned long long*)&v)[0],
                         __ATOMIC_RELAXED, __HIP_MEMORY_SCOPE_AGENT);
      __hip_atomic_store((unsigned long long*)(dst + 4), ((const unsigned long long*)&v)[1],
                         __ATOMIC_RELAXED, __HIP_MEMORY_SCOPE_AGENT);
      asm volatile("s_waitcnt vmcnt(0)" ::: "memory");
      if (lane == 0)
        __hip_atomic_store(flown + s, t + 1, __ATOMIC_RELAXED, __HIP_MEMORY_SCOPE_AGENT);
      const int row = (g * 16 + (lane >> 2)) * 64 + t;
      *(uint4*)(hcat + (size_t)row * 1024 + colbase + (lane & 3) * 8) = v;
    }
  }
}

// ================= fused prep head: casts + weight perms + gather + flag clear =======
struct CastJobs {
  const float* src[12];
  unsigned short* dst[12];
  long nreal4[12];
  long cum4[13];
  int n;
};

struct Prep0Args {
  CastJobs J;
  const float *Wv1, *Wv2, *Wihl1, *Wihl2, *b1, *b2;
  const float *bih1, *bic1, *bih2, *bic2;
  const float *Wo1, *bv1, *bo1, *Wo2, *bv2, *bo2;
  unsigned short *WvT1, *WvT2, *Wp1, *Wp2;
  float *bp1, *bp2, *bcat, *bc1, *bc2;
  const int* ix; const float* emb; unsigned short* x_b;
  int* flags;
};

// grid 5121 x 256: [0,2048) casts | [2048,3072) prep | [3072,5120) gather | 5120 flags
__global__ __launch_bounds__(256) void prep0(Prep0Args A) {
  const int bid = blockIdx.x, tid = threadIdx.x;
  if (bid < 2048) {
    const CastJobs& J = A.J;
    const long total = J.cum4[J.n];
    for (long i = (long)bid * 256 + tid; i < total; i += (long)2048 * 256) {
      int s = 0;
      while (i >= J.cum4[s + 1]) ++s;
      const long off = i - J.cum4[s];
      float4 v = {0.f, 0.f, 0.f, 0.f};
      if (off < J.nreal4[s]) v = ((const float4*)J.src[s])[off];
      ushort4 o;
      o.x = f2bf(v.x); o.y = f2bf(v.y); o.z = f2bf(v.z); o.w = f2bf(v.w);
      ((ushort4*)J.dst[s])[off] = o;
    }
  } else if (bid < 3072) {
    const long NTOT = 924672;
    for (long id = (long)(bid - 2048) * 256 + tid; id < NTOT; id += (long)1024 * 256) {
      if (id < 131072) {              // perm W_ih1 by-8
        const int m = (int)(id >> 6), kb = (int)(id & 63) * 8;
        const float* sp = A.Wihl1 + (size_t)((m & 3) * 512 + (m >> 2)) * 512 + kb;
        unsigned short o[8];
#pragma unroll
        for (int e = 0; e < 8; ++e) o[e] = f2bf(sp[e]);
        *(uint4*)(A.Wp1 + (size_t)m * 512 + kb) = *(const uint4*)o;
      } else if (id < 393216) {       // perm W_ih2 by-8
        const long j = id - 131072;
        const int m = (int)(j >> 7), kb = (int)(j & 127) * 8;
        const float* sp = A.Wihl2 + (size_t)((m & 3) * 512 + (m >> 2)) * 1024 + kb;
        unsigned short o[8];
#pragma unroll
        for (int e = 0; e < 8; ++e) o[e] = f2bf(sp[e]);
        *(uint4*)(A.Wp2 + (size_t)m * 1024 + kb) = *(const uint4*)o;
      } else if (id < 917504) {       // transposed cast of Wv1/Wv2
        const long t = id - 393216;
        const int which = (int)(t >> 18);
        const int u = (int)(t & 262143), a = u >> 9, bb = u & 511;
        (which ? A.WvT2 : A.WvT1)[u] = f2bf((which ? A.Wv2 : A.Wv1)[(size_t)bb * 512 + a]);
      } else if (id < 921600) {       // bias perms
        const int t = (int)(id - 917504);
        if (t < 2048) A.bp1[t] = A.b1[(t & 3) * 512 + (t >> 2)];
        else { const int m = t - 2048; A.bp2[m] = A.b2[(m & 3) * 512 + (m >> 2)]; }
      } else if (id < 923648) {       // bcat concat
        const int i = (int)(id - 921600);
        const float* sarr[4] = {A.bih1, A.bic1, A.bih2, A.bic2};
        A.bcat[i] = sarr[i >> 9][i & 511];
      } else {                        // bc = Wo @ bv + bo (1024 rows)
        const int i = (int)(id - 923648);
        const float* Wo = (i >= 512) ? A.Wo2 : A.Wo1;
        const float* bv = (i >= 512) ? A.bv2 : A.bv1;
        const float* bo = (i >= 512) ? A.bo2 : A.bo1;
        float* bc = (i >= 512) ? A.bc2 : A.bc1;
        const int r = i & 511;
        float sacc = bo[r];
        for (int k = 0; k < 512; k += 4) {
          const float4 wv = *(const float4*)(Wo + (size_t)r * 512 + k);
          const float4 bb = *(const float4*)(bv + k);
          sacc += wv.x * bb.x + wv.y * bb.y + wv.z * bb.z + wv.w * bb.w;
        }
        bc[r] = sacc;
      }
    }
  } else if (bid < 5120) {
    // gather + cast: 4 rows per block
    const int row = (bid - 3072) * 4 + (tid >> 6);
    const int lane = tid & 63;
    const int e = A.ix[row];
    const float4* s = (const float4*)(A.emb + (size_t)e * 512) + lane * 2;
    const float4 a = s[0], b = s[1];
    unsigned short o[8] = {f2bf(a.x), f2bf(a.y), f2bf(a.z), f2bf(a.w),
                           f2bf(b.x), f2bf(b.y), f2bf(b.z), f2bf(b.w)};
    *(uint4*)(A.x_b + (size_t)row * 512 + lane * 8) = *(const uint4*)o;
  } else {
    // zero flags (512 ints)
    A.flags[tid] = 0;
    A.flags[tid + 256] = 0;
  }
}

// Combined: reorder_wbf (blocks [0,512)) + beff2 (blocks [512,1024)) + blcat (rest)
__global__ void combo(const unsigned short* __restrict__ W, unsigned short* __restrict__ R,
                      const unsigned short* __restrict__ Wl, const float* __restrict__ blog,
                      const unsigned short* __restrict__ Wp2, const float* __restrict__ bp2,
                      const float* __restrict__ bc1, const float* __restrict__ bc2,
                      float* __restrict__ blcat, float* __restrict__ beff2) {
  const int lane = threadIdx.x & 63;
  if (blockIdx.x < 512) {
    const int id = blockIdx.x * 256 + threadIdx.x;  // 131072
    const int tid = id & 255, mi = (id >> 8) & 1, kk = (id >> 9) & 15, s = id >> 13;
    const int w = tid >> 6, ln = tid & 63, fr = ln & 15, kq = ln >> 4;
    const int row = s * 128 + w * 32 + mi * 16 + fr;
    const int col = kk * 32 + kq * 8;
    *((uint4*)R + id) = *(const uint4*)(W + (size_t)row * 512 + col);
  } else if (blockIdx.x < 1024) {
    const int m = (blockIdx.x - 512) * 4 + (threadIdx.x >> 6);
    const unsigned short* row = Wp2 + (size_t)m * 1024 + 512;
    float sum = 0.f;
    for (int k = lane; k < 512; k += 64) sum += bf2f(row[k]) * bc1[k];
#pragma unroll
    for (int mm = 32; mm; mm >>= 1) sum += __shfl_xor(sum, mm, 64);
    if (lane == 0) beff2[m] = bp2[m] + sum;
  } else {
    const int j = (blockIdx.x - 1024) * 4 + (threadIdx.x >> 6);  // < 10000
    const unsigned short* row = Wl + (size_t)j * 1536;
    float sum = 0.f;
    for (int k = lane; k < 512; k += 64) {
      sum += bf2f(row[512 + k]) * bc1[k];
      sum += bf2f(row[1024 + k]) * bc2[k];
    }
#pragma unroll
    for (int mm = 32; mm; mm >>= 1) sum += __shfl_xor(sum, mm, 64);
    if (lane == 0) blcat[j] = blog[j] + sum;
  }
}

// ================= host =================
extern "C" void kernel_launch(void* const* d_in, const int* in_sizes, int n_in,
                              void* d_out, int out_size, void* d_ws, size_t ws_size,
                              hipStream_t stream) {
  (void)in_sizes; (void)n_in; (void)out_size; (void)ws_size;
  const float* img    = (const float*)d_in[0];
  const int*   ix     = (const int*)d_in[1];
  const float* emb    = (const float*)d_in[2];
  const float* Wih1f  = (const float*)d_in[3];
  const float* bih1   = (const float*)d_in[4];
  const float* Wic1f  = (const float*)d_in[5];
  const float* bic1   = (const float*)d_in[6];
  const float* Wih2f  = (const float*)d_in[7];
  const float* bih2   = (const float*)d_in[8];
  const float* Wic2f  = (const float*)d_in[9];
  const float* bic2   = (const float*)d_in[10];
  const float* Wihl1  = (const float*)d_in[11];
  const float* Whhl1  = (const float*)d_in[12];
  const float* b1     = (const float*)d_in[13];
  const float* Wihl2  = (const float*)d_in[14];
  const float* Whhl2  = (const float*)d_in[15];
  const float* b2     = (const float*)d_in[16];
  const float* Wv1    = (const float*)d_in[17];
  const float* bv1    = (const float*)d_in[18];
  const float* Wo1    = (const float*)d_in[19];
  const float* bo1    = (const float*)d_in[20];
  const float* Wv2    = (const float*)d_in[21];
  const float* bv2    = (const float*)d_in[22];
  const float* Wo2    = (const float*)d_in[23];
  const float* bo2    = (const float*)d_in[24];
  const float* Wlog   = (const float*)d_in[25];
  const float* blog   = (const float*)d_in[26];
  float* out = (float*)d_out;

  char* p = (char*)d_ws;
  auto al = [&](size_t bytes) { char* r = p; p += (bytes + 255) & ~(size_t)255; return r; };
  unsigned short* Wp1    = (unsigned short*)al((size_t)2048 * 512 * 2);
  unsigned short* Whh1_b = (unsigned short*)al((size_t)2048 * 512 * 2);
  unsigned short* Wp2    = (unsigned short*)al((size_t)2048 * 1024 * 2);
  unsigned short* Whh2_b = (unsigned short*)al((size_t)2048 * 512 * 2);
  unsigned short* WvT1   = (unsigned short*)al((size_t)512 * 512 * 2);
  unsigned short* Wo1_b  = (unsigned short*)al((size_t)512 * 512 * 2);
  unsigned short* WvT2   = (unsigned short*)al((size_t)512 * 512 * 2);
  unsigned short* Wo2_b  = (unsigned short*)al((size_t)512 * 512 * 2);
  unsigned short* Wc1T   = (unsigned short*)al((size_t)512 * 512 * 2);
  unsigned short* Wc2T   = (unsigned short*)al((size_t)512 * 512 * 2);
  unsigned short* Wlog_b = (unsigned short*)al((size_t)10240 * 1536 * 2);
  unsigned short* Wcat   = (unsigned short*)al((size_t)10240 * 1024 * 2);
  unsigned short* Weff2  = (unsigned short*)al((size_t)2048 * 512 * 2);
  unsigned short* Weff2r = (unsigned short*)al((size_t)2048 * 512 * 2);
  unsigned short* Wh1i_b = (unsigned short*)al((size_t)512 * 2048 * 2);
  unsigned short* Wc1i_b = (unsigned short*)al((size_t)512 * 2048 * 2);
  unsigned short* Wh2i_b = (unsigned short*)al((size_t)512 * 2048 * 2);
  unsigned short* Wc2i_b = (unsigned short*)al((size_t)512 * 2048 * 2);
  unsigned short* img_b  = (unsigned short*)al((size_t)128 * 2048 * 2);
  unsigned short* x_b    = (unsigned short*)al((size_t)8192 * 512 * 2);
  float*          xpr    = (float*)al((size_t)8192 * 2048 * 4);
  unsigned short* hcat   = (unsigned short*)al((size_t)8192 * 1024 * 2);
  unsigned short* hx1    = (unsigned short*)al((size_t)64 * 128 * 512 * 2);
  unsigned short* hx2    = (unsigned short*)al((size_t)64 * 128 * 512 * 2);
  unsigned short* h01    = (unsigned short*)al((size_t)128 * 512 * 2);
  unsigned short* h02    = (unsigned short*)al((size_t)128 * 512 * 2);
  float*          c1st   = (float*)al((size_t)128 * 512 * 4);
  float*          c2st   = (float*)al((size_t)128 * 512 * 4);
  float*          bcat   = (float*)al((size_t)2048 * 4);
  float*          bp1    = (float*)al((size_t)2048 * 4);
  float*          bp2    = (float*)al((size_t)2048 * 4);
  float*          bc1    = (float*)al((size_t)512 * 4);
  float*          bc2    = (float*)al((size_t)512 * 4);
  float*          beff2  = (float*)al((size_t)2048 * 4);
  float*          blcat  = (float*)al((size_t)10240 * 4);
  int*            flags  = (int*)al(2048);

  // ---- fused prep head: casts + perms + gather + flag clear ----
  Prep0Args PA = {};
  auto addjob = [&](const float* s, unsigned short* d, long nreal, long ntot) {
    PA.J.src[PA.J.n] = s; PA.J.dst[PA.J.n] = d; PA.J.nreal4[PA.J.n] = nreal / 4;
    PA.J.cum4[PA.J.n + 1] = PA.J.cum4[PA.J.n] + ntot / 4; ++PA.J.n;
  };
  addjob(img,   img_b,  (long)128 * 2048,   (long)128 * 2048);
  addjob(Whhl1, Whh1_b, (long)2048 * 512,   (long)2048 * 512);
  addjob(Whhl2, Whh2_b, (long)2048 * 512,   (long)2048 * 512);
  addjob(Wo1,   Wo1_b,  (long)512 * 512,    (long)512 * 512);
  addjob(Wo2,   Wo2_b,  (long)512 * 512,    (long)512 * 512);
  addjob(Wih1f, Wh1i_b, (long)512 * 2048,   (long)512 * 2048);
  addjob(Wic1f, Wc1i_b, (long)512 * 2048,   (long)512 * 2048);
  addjob(Wih2f, Wh2i_b, (long)512 * 2048,   (long)512 * 2048);
  addjob(Wic2f, Wc2i_b, (long)512 * 2048,   (long)512 * 2048);
  addjob(Wlog,  Wlog_b, (long)10000 * 1536, (long)10240 * 1536);
  PA.Wv1 = Wv1; PA.Wv2 = Wv2; PA.Wihl1 = Wihl1; PA.Wihl2 = Wihl2;
  PA.b1 = b1; PA.b2 = b2;
  PA.bih1 = bih1; PA.bic1 = bic1; PA.bih2 = bih2; PA.bic2 = bic2;
  PA.Wo1 = Wo1; PA.bv1 = bv1; PA.bo1 = bo1; PA.Wo2 = Wo2; PA.bv2 = bv2; PA.bo2 = bo2;
  PA.WvT1 = WvT1; PA.WvT2 = WvT2; PA.Wp1 = Wp1; PA.Wp2 = Wp2;
  PA.bp1 = bp1; PA.bp2 = bp2; PA.bcat = bcat; PA.bc1 = bc1; PA.bc2 = bc2;
  PA.ix = ix; PA.emb = emb; PA.x_b = x_b; PA.flags = flags;
  prep0<<<5121, 256, 0, stream>>>(PA);

  // ---- batch A: xp1 (MODE2) | WcT1 | WcT2 (MODE1) | init (MODE3) ----
  {
    GJobs B = {};
    B.j[0] = {Wp1, x_b, xpr, nullptr, nullptr, nullptr, bp1,
              512, 512, 0, 0, 512, 8192, 16, 2, 1024, 0};
    B.j[1] = {WvT1, Wo1_b, Wc1T, nullptr, nullptr, nullptr, nullptr,
              512, 512, 512, 0, 512, 512, 4, 1, 1040, 0};
    B.j[2] = {WvT2, Wo2_b, Wc2T, nullptr, nullptr, nullptr, nullptr,
              512, 512, 512, 0, 512, 512, 4, 1, 1056, 0};
    B.j[3] = {img_b, Wh1i_b, h01, c1st, h02, c2st, bcat,
              2048, 2048, 0, 0, 2048, 2048, 1, 3, 1072, 0};
    gemm_batch<<<1072, 256, 0, stream>>>(B);
  }

  // ---- batch B: Wcat-a (MODE4) | Wcat-b (MODE1) | Weff2 fold (MODE4) ----
  {
    GJobs B = {};
    B.j[0] = {Wlog_b + 1024, Wc2T, Wcat, Wlog_b, nullptr, nullptr, nullptr,
              1536, 512, 1024, 1536, 512, 512, 80, 4, 320, 0};
    B.j[1] = {Wlog_b + 512, Wc1T, Wcat + 512, nullptr, nullptr, nullptr, nullptr,
              1536, 512, 1024, 0, 512, 512, 80, 1, 640, 0};
    B.j[2] = {Wp2 + 512, Wc1T, Weff2, Wp2, nullptr, nullptr, nullptr,
              1024, 512, 512, 1024, 512, 512, 16, 4, 704, 0};
    gemm_batch<<<704, 256, 0, stream>>>(B);
  }

  // ---- combo: reorder Weff2 + beff2 + blcat ----
  combo<<<3524, 256, 0, stream>>>(Weff2, Weff2r, Wlog_b, blog, Wp2, bp2,
                                  bc1, bc2, blcat, beff2);

  // ---- both LSTMs, fused & pipelined (R13-exact) ----
  lstm_fused<<<256, 256, 0, stream>>>(
      Whh1_b, Whh2_b, Weff2r, h01, h02, c1st, c2st, xpr, beff2, hx1, hx2, hcat, flags);

  // ---- logits = hcat @ Wcat^T + blcat (n-major tile order) ----
  gemm256<<<dim3(40, 32), 512, 0, stream>>>(
      hcat, 1024, Wcat, 1024, out, 10000, blcat, 1024, 10000);
}